// Round 9
// baseline (134.866 us; speedup 1.0000x reference)
//
#include <hip/hip_runtime.h>

#define TPB 256
constexpr int B_ = 8, C_ = 192, H_ = 56, W_ = 56, O_ = 384;
constexpr int HW_ = H_ * W_;          // 3136
constexpr int NOFF = 18;              // 9 taps * 2 (dy,dx)
constexpr int NPIX = B_ * HW_;        // 25088 = 196 * 128

typedef __attribute__((ext_vector_type(8))) short short8v;
typedef __attribute__((ext_vector_type(4))) float f32x4;

__device__ inline unsigned short f2bf(float f) {
  unsigned u = __builtin_bit_cast(unsigned, f);
  unsigned r = (u + 0x7fffu + ((u >> 16) & 1u)) >> 16;
  return (unsigned short)r;
}
__device__ inline float bflo(unsigned u) {
  return __builtin_bit_cast(float, u << 16);
}
__device__ inline float bfhi(unsigned u) {
  return __builtin_bit_cast(float, u & 0xffff0000u);
}

// ---------------- K0: pw_w (O,C) fp32 -> bf16 same layout ----------------
__global__ __launch_bounds__(TPB) void k_wb(const float* __restrict__ pw,
                                            unsigned short* __restrict__ wtb) {
  int i = blockIdx.x * TPB + threadIdx.x;
  if (i < O_ * C_) wtb[i] = f2bf(pw[i]);
}

// ---------------- K1: depthwise 3x3, pad 1 (elementwise, full grid) -------
__global__ __launch_bounds__(TPB) void k_dw(const float* __restrict__ x,
                                            const float* __restrict__ wdw,
                                            float* __restrict__ t1) {
  int idx = blockIdx.x * TPB + threadIdx.x;
  if (idx >= B_ * C_ * HW_) return;
  int w = idx % W_;
  int h = (idx / W_) % H_;
  int c = (idx / HW_) % C_;
  const float* wp = wdw + c * 9;
  float acc = 0.f;
#pragma unroll
  for (int i = 0; i < 3; ++i) {
    int hh = h + i - 1;
    if ((unsigned)hh >= (unsigned)H_) continue;
#pragma unroll
    for (int j = 0; j < 3; ++j) {
      int ww = w + j - 1;
      if ((unsigned)ww >= (unsigned)W_) continue;
      acc += x[idx + (i - 1) * W_ + (j - 1)] * wp[i * 3 + j];
    }
  }
  t1[idx] = acc;
}

// ---- K2: pointwise C->18 + clip; block = 64px x all 18ch, t1 staged once --
__global__ __launch_bounds__(TPB) void k_pw18b(const float* __restrict__ t1,
                                               const float* __restrict__ wpw,
                                               float* __restrict__ offp) {
  __shared__ float st[C_ * 64];       // 48 KB, [c][px]
  int tid = threadIdx.x;
  int P0 = blockIdx.x * 64;
  int b = blockIdx.y;
  const float* tb = t1 + (size_t)b * C_ * HW_ + P0;
#pragma unroll
  for (int i = 0; i < 48; ++i) {
    int idx = i * TPB + tid;
    int c = idx >> 6, px = idx & 63;
    st[c * 64 + px] = tb[(size_t)c * HW_ + px];
  }
  __syncthreads();

  int px = tid & 63;
  int g = tid >> 6;                   // 0..3; channels g, g+4, g+8, g+12, (g+16 if g<2)
  float acc[5] = {0.f, 0.f, 0.f, 0.f, 0.f};
  const float* w0 = wpw + (g + 0) * C_;
  const float* w1 = wpw + (g + 4) * C_;
  const float* w2 = wpw + (g + 8) * C_;
  const float* w3 = wpw + (g + 12) * C_;
  const float* w4 = wpw + (g + 16) * C_;  // valid only if g<2
  bool has5 = (g < 2);
  for (int c = 0; c < C_; ++c) {
    float v = st[c * 64 + px];
    acc[0] += v * w0[c];
    acc[1] += v * w1[c];
    acc[2] += v * w2[c];
    acc[3] += v * w3[c];
    if (has5) acc[4] += v * w4[c];
  }
  float* ob = offp + (size_t)b * NOFF * HW_ + P0 + px;
#pragma unroll
  for (int j = 0; j < 4; ++j)
    ob[(size_t)(g + 4 * j) * HW_] = fminf(fmaxf(acc[j], -1.f), 1.f);
  if (has5)
    ob[(size_t)(g + 16) * HW_] = fminf(fmaxf(acc[4], -1.f), 1.f);
}

// ---------------- K_XT: x[b][c][h][w] fp32 -> x_t[b][hw][c] bf16 ----------
__global__ __launch_bounds__(TPB) void k_xt(const float* __restrict__ x,
                                            unsigned short* __restrict__ xt) {
  __shared__ unsigned short tile[64 * 198];
  int tid = threadIdx.x;
  int P0 = blockIdx.x * 64;
  int b = blockIdx.y;
#pragma unroll
  for (int i = 0; i < 48; ++i) {
    int idx = i * TPB + tid;
    int px = idx & 63;
    int c = idx >> 6;
    float v = x[((size_t)(b * C_ + c)) * HW_ + P0 + px];
    tile[px * 198 + c] = f2bf(v);
  }
  __syncthreads();
  unsigned* xtu = (unsigned*)xt;
#pragma unroll
  for (int i = 0; i < 24; ++i) {
    int d = i * TPB + tid;            // dword index in 64*96
    int px = d / 96;
    int c2 = d - px * 96;
    unsigned v = *(const unsigned*)&tile[px * 198 + c2 * 2];
    xtu[((size_t)b * HW_ + P0 + px) * 96 + c2] = v;
  }
}

// ------- K3: deform sample + dcn; tap-split 3-way, bf16 partial buffers ---
__global__ __launch_bounds__(TPB) void k_deform7(const unsigned short* __restrict__ xt,
                                                 const float* __restrict__ offp,
                                                 const float* __restrict__ dcn,
                                                 unsigned short* __restrict__ y1p) {
  __shared__ __align__(16) float dcnT[3 * C_];
  int tid = threadIdx.x;
  int kt0 = blockIdx.y * 3;
  for (int t = tid; t < 3 * C_; t += TPB) {
    int k = t / C_, c = t - k * C_;
    dcnT[t] = dcn[c * 9 + kt0 + k];
  }
  __syncthreads();
  y1p += (size_t)blockIdx.y * NPIX * C_;

  int px = blockIdx.x * 16 + (tid >> 4);
  int lg = tid & 15;
  int b = px / HW_;
  int hw = px - b * HW_;
  int h = hw / W_;
  int w = hw - h * W_;
  const float* op = offp + (size_t)b * NOFF * HW_ + hw;
  int pb = b * HW_;

  float acc[12];
#pragma unroll
  for (int j = 0; j < 12; ++j) acc[j] = 0.f;

#pragma unroll
  for (int k3 = 0; k3 < 3; ++k3) {
    int tap = kt0 + k3;
    int t3 = tap / 3;
    int ky = t3 - 1;
    int kx = tap - t3 * 3 - 1;
    float dy = op[(2 * tap) * HW_];
    float dx = op[(2 * tap + 1) * HW_];
    float ys = (float)(h + ky) + dy;
    float xs = (float)(w + kx) + dx;
    float y0f = floorf(ys), x0f = floorf(xs);
    float ty = ys - y0f, tx = xs - x0f;
    int y0 = (int)y0f, x0 = (int)x0f;
    int y1 = y0 + 1, x1 = x0 + 1;
    float fy0 = ((unsigned)y0 < (unsigned)H_) ? 1.f : 0.f;
    float fy1 = ((unsigned)y1 < (unsigned)H_) ? 1.f : 0.f;
    float fx0 = ((unsigned)x0 < (unsigned)W_) ? 1.f : 0.f;
    float fx1 = ((unsigned)x1 < (unsigned)W_) ? 1.f : 0.f;
    int y0c = y0 < 0 ? 0 : (y0 > H_ - 1 ? H_ - 1 : y0);
    int y1c = y1 < 0 ? 0 : (y1 > H_ - 1 ? H_ - 1 : y1);
    int x0c = x0 < 0 ? 0 : (x0 > W_ - 1 ? W_ - 1 : x0);
    int x1c = x1 < 0 ? 0 : (x1 > W_ - 1 ? W_ - 1 : x1);
    float omty = 1.f - ty, omtx = 1.f - tx;
    float w00 = omty * omtx * fy0 * fx0;
    float w01 = omty * tx * fy0 * fx1;
    float w10 = ty * omtx * fy1 * fx0;
    float w11 = ty * tx * fy1 * fx1;
    int r0 = (pb + y0c * W_) * C_;
    int r1 = (pb + y1c * W_) * C_;
    int p00 = r0 + x0c * C_;
    int p01 = r0 + x1c * C_;
    int p10 = r1 + x0c * C_;
    int p11 = r1 + x1c * C_;
#pragma unroll
    for (int rep = 0; rep < 3; ++rep) {
      int c0 = lg * 4 + rep * 64;
      uint2 u00 = *(const uint2*)(xt + p00 + c0);
      uint2 u01 = *(const uint2*)(xt + p01 + c0);
      uint2 u10 = *(const uint2*)(xt + p10 + c0);
      uint2 u11 = *(const uint2*)(xt + p11 + c0);
      f32x4 dw = *(const f32x4*)&dcnT[k3 * C_ + c0];
      float s0 = w00 * bflo(u00.x) + w01 * bflo(u01.x) + w10 * bflo(u10.x) + w11 * bflo(u11.x);
      float s1 = w00 * bfhi(u00.x) + w01 * bfhi(u01.x) + w10 * bfhi(u10.x) + w11 * bfhi(u11.x);
      float s2 = w00 * bflo(u00.y) + w01 * bflo(u01.y) + w10 * bflo(u10.y) + w11 * bflo(u11.y);
      float s3 = w00 * bfhi(u00.y) + w01 * bfhi(u01.y) + w10 * bfhi(u10.y) + w11 * bfhi(u11.y);
      acc[rep * 4 + 0] += s0 * dw.x;
      acc[rep * 4 + 1] += s1 * dw.y;
      acc[rep * 4 + 2] += s2 * dw.z;
      acc[rep * 4 + 3] += s3 * dw.w;
    }
  }

  int ob = px * C_ + lg * 4;
#pragma unroll
  for (int rep = 0; rep < 3; ++rep) {
    uint2 pk;
    pk.x = (unsigned)f2bf(acc[rep * 4 + 0]) | ((unsigned)f2bf(acc[rep * 4 + 1]) << 16);
    pk.y = (unsigned)f2bf(acc[rep * 4 + 2]) | ((unsigned)f2bf(acc[rep * 4 + 3]) << 16);
    *(uint2*)(y1p + ob + rep * 64) = pk;
  }
}

// ---- K4: one block = 64 px x ALL 384 O; bf16 partials read once ----------
__global__ __launch_bounds__(TPB) void k_gemm3b(const unsigned short* __restrict__ y1p,
                                                const unsigned short* __restrict__ wtb,
                                                float* __restrict__ out) {
  __shared__ __align__(16) unsigned short bsm[64 * 192];  // 24 KB
  int tid = threadIdx.x;
  int n0 = blockIdx.x * 64;

  const unsigned short* s0 = y1p + (size_t)n0 * C_;
  const unsigned short* s1 = s0 + (size_t)NPIX * C_;
  const unsigned short* s2 = s1 + (size_t)NPIX * C_;
  char* sbase = (char*)bsm;
#pragma unroll
  for (int i = 0; i < 12; ++i) {
    int u = i * TPB + tid;            // 8B-dst unit: 64 rows x 48 units
    int row = u / 48;
    int cu = u - row * 48;
    int so = row * 192 + cu * 4;
    uint2 a = *(const uint2*)(s0 + so);
    uint2 b4 = *(const uint2*)(s1 + so);
    uint2 c4 = *(const uint2*)(s2 + so);
    float v0 = bflo(a.x) + bflo(b4.x) + bflo(c4.x);
    float v1 = bfhi(a.x) + bfhi(b4.x) + bfhi(c4.x);
    float v2 = bflo(a.y) + bflo(b4.y) + bflo(c4.y);
    float v3 = bfhi(a.y) + bfhi(b4.y) + bfhi(c4.y);
    uint2 pk;
    pk.x = (unsigned)f2bf(v0) | ((unsigned)f2bf(v1) << 16);
    pk.y = (unsigned)f2bf(v2) | ((unsigned)f2bf(v3) << 16);
    *(uint2*)(sbase + row * 384 + ((cu * 8) ^ ((row & 7) << 4))) = pk;
  }
  __syncthreads();

  int wid = tid >> 6;
  int lane = tid & 63;
  int col = lane & 15;
  int kg = lane >> 4;
  int wr = wid >> 1;                  // O-half (0,1)
  int wc = wid & 1;                   // px-half (0,1)

#pragma unroll 1
  for (int m0 = 0; m0 < O_; m0 += 64) {
    f32x4 acc[2][2];
#pragma unroll
    for (int mf = 0; mf < 2; ++mf)
#pragma unroll
      for (int nf = 0; nf < 2; ++nf) acc[mf][nf] = (f32x4){0.f, 0.f, 0.f, 0.f};

#pragma unroll
    for (int k0 = 0; k0 < C_; k0 += 32) {
      short8v a[2], bfr[2];
#pragma unroll
      for (int mf = 0; mf < 2; ++mf)
        a[mf] = *(const short8v*)(wtb + (m0 + wr * 32 + mf * 16 + col) * C_ + k0 + kg * 8);
#pragma unroll
      for (int nf = 0; nf < 2; ++nf) {
        int brow = wc * 32 + nf * 16 + col;
        int kb = (k0 + kg * 8) * 2;
        bfr[nf] = *(const short8v*)(sbase + brow * 384 + (kb ^ ((brow & 7) << 4)));
      }
#pragma unroll
      for (int mf = 0; mf < 2; ++mf)
#pragma unroll
        for (int nf = 0; nf < 2; ++nf)
          acc[mf][nf] = __builtin_amdgcn_mfma_f32_16x16x32_bf16(a[mf], bfr[nf], acc[mf][nf], 0, 0, 0);
    }

#pragma unroll
    for (int mf = 0; mf < 2; ++mf) {
#pragma unroll
      for (int nf = 0; nf < 2; ++nf) {
        int p = n0 + wc * 32 + nf * 16 + col;
        int bb = p / HW_;
        int hw = p - bb * HW_;
#pragma unroll
        for (int reg = 0; reg < 4; ++reg) {
          int o = m0 + wr * 32 + mf * 16 + kg * 4 + reg;
          float a = acc[mf][nf][reg];
          float r = a * fminf(fmaxf(a + 3.f, 0.f), 6.f) * (1.f / 6.f);
          out[((size_t)bb * O_ + o) * HW_ + hw] = r;
        }
      }
    }
  }
}

extern "C" void kernel_launch(void* const* d_in, const int* in_sizes, int n_in,
                              void* d_out, int out_size, void* d_ws, size_t ws_size,
                              hipStream_t stream) {
  const float* x = (const float*)d_in[0];
  const float* og_dw = (const float*)d_in[1];
  const float* og_pw = (const float*)d_in[2];
  const float* dcn_w = (const float*)d_in[3];
  const float* pw_w = (const float*)d_in[4];
  float* out = (float*)d_out;

  float* ws = (float*)d_ws;
  float* t1 = ws;                                        // B*C*HW fp32
  float* offp = t1 + (size_t)B_ * C_ * HW_;              // B*18*HW fp32
  unsigned short* y1p = (unsigned short*)(offp + (size_t)B_ * NOFF * HW_);  // 3*NPIX*C bf16
  unsigned short* wtb = y1p + 3 * (size_t)NPIX * C_;     // O*C bf16
  unsigned short* x_t = wtb + (size_t)O_ * C_;           // NPIX*C bf16

  k_wb<<<(O_ * C_ + TPB - 1) / TPB, TPB, 0, stream>>>(pw_w, wtb);
  k_dw<<<(B_ * C_ * HW_ + TPB - 1) / TPB, TPB, 0, stream>>>(x, og_dw, t1);
  k_xt<<<dim3(HW_ / 64, B_), TPB, 0, stream>>>(x, x_t);
  k_pw18b<<<dim3(HW_ / 64, B_), TPB, 0, stream>>>(t1, og_pw, offp);
  k_deform7<<<dim3(NPIX / 16, 3), TPB, 0, stream>>>(x_t, offp, dcn_w, y1p);
  k_gemm3b<<<NPIX / 64, TPB, 0, stream>>>(y1p, wtb, out);
}

// Round 10
// 110.434 us; speedup vs baseline: 1.2212x; 1.2212x over previous
//
#include <hip/hip_runtime.h>

#define TPB 256
constexpr int B_ = 8, C_ = 192, H_ = 56, W_ = 56, O_ = 384;
constexpr int HW_ = H_ * W_;          // 3136
constexpr int NOFF = 18;              // 9 taps * 2 (dy,dx)
constexpr int NPIX = B_ * HW_;        // 25088 = 196 * 128
constexpr int K2 = 9 * C_;            // 1728 combined-conv K

typedef __attribute__((ext_vector_type(8))) short short8v;
typedef __attribute__((ext_vector_type(4))) float f32x4;

__device__ inline unsigned short f2bf(float f) {
  unsigned u = __builtin_bit_cast(unsigned, f);
  unsigned r = (u + 0x7fffu + ((u >> 16) & 1u)) >> 16;
  return (unsigned short)r;
}
__device__ inline float bflo(unsigned u) {
  return __builtin_bit_cast(float, u << 16);
}
__device__ inline float bfhi(unsigned u) {
  return __builtin_bit_cast(float, u & 0xffff0000u);
}

// ---------------- K0: pw_w (O,C) fp32 -> bf16 same layout ----------------
__global__ __launch_bounds__(TPB) void k_wb(const float* __restrict__ pw,
                                            unsigned short* __restrict__ wtb) {
  int i = blockIdx.x * TPB + threadIdx.x;
  if (i < O_ * C_) wtb[i] = f2bf(pw[i]);
}

// ---- K_W2: combined offset-conv weight W2[32][1728] bf16 (rows>=18 zero) --
// W2[o][tap*192+c] = og_pw[o][c] * og_dw[c][tap]
__global__ __launch_bounds__(TPB) void k_w2(const float* __restrict__ og_dw,
                                            const float* __restrict__ og_pw,
                                            unsigned short* __restrict__ w2b) {
  int i = blockIdx.x * TPB + threadIdx.x;  // 32*1728 = 55296
  if (i >= 32 * K2) return;
  int o = i / K2, k = i - o * K2;
  int tap = k / C_, c = k - tap * C_;
  float v = 0.f;
  if (o < NOFF) v = og_pw[o * C_ + c] * og_dw[c * 9 + tap];
  w2b[i] = f2bf(v);
}

// ---------------- K_XT: x[b][c][h][w] fp32 -> x_t[b][hw][c] bf16 ----------
__global__ __launch_bounds__(TPB) void k_xt(const float* __restrict__ x,
                                            unsigned short* __restrict__ xt) {
  __shared__ unsigned short tile[64 * 198];
  int tid = threadIdx.x;
  int P0 = blockIdx.x * 64;
  int b = blockIdx.y;
#pragma unroll
  for (int i = 0; i < 48; ++i) {
    int idx = i * TPB + tid;
    int px = idx & 63;
    int c = idx >> 6;
    float v = x[((size_t)(b * C_ + c)) * HW_ + P0 + px];
    tile[px * 198 + c] = f2bf(v);
  }
  __syncthreads();
  unsigned* xtu = (unsigned*)xt;
#pragma unroll
  for (int i = 0; i < 24; ++i) {
    int d = i * TPB + tid;            // dword index in 64*96
    int px = d / 96;
    int c2 = d - px * 96;
    unsigned v = *(const unsigned*)&tile[px * 198 + c2 * 2];
    xtu[((size_t)b * HW_ + P0 + px) * 96 + c2] = v;
  }
}

// ---- K_OFF: fused dw3x3+pw18 as im2col MFMA; block = 8x8 px, halo 10x10 --
__global__ __launch_bounds__(TPB) void k_off(const unsigned short* __restrict__ xt,
                                             const unsigned short* __restrict__ w2b,
                                             float* __restrict__ offp) {
  __shared__ __align__(16) unsigned short hal[100 * 192];  // 38.4 KB
  int tid = threadIdx.x;
  int w0 = blockIdx.x * 8;
  int h0 = blockIdx.y * 8;
  int b = blockIdx.z;

  // stage halo rows h0-1..h0+8, cols w0-1..w0+8; zero-fill OOB; XOR-swizzle
  char* sb = (char*)hal;
  const unsigned* xu = (const unsigned*)xt;
  for (int i = 0; i < 38; ++i) {
    int u = i * TPB + tid;            // dword unit: 100 pos x 96 dwords
    if (u < 9600) {
      int pos = u / 96, c2 = u - pos * 96;
      int py = pos / 10;
      int gy = h0 - 1 + py;
      int gx = w0 - 1 + (pos - py * 10);
      unsigned v = 0;
      if ((unsigned)gy < (unsigned)H_ && (unsigned)gx < (unsigned)W_)
        v = xu[((size_t)b * HW_ + gy * W_ + gx) * 96 + c2];
      *(unsigned*)(sb + pos * 384 + ((c2 * 4) ^ ((pos & 7) << 4))) = v;
    }
  }
  __syncthreads();

  int wid = tid >> 6;
  int lane = tid & 63;
  int col = lane & 15;
  int kg = lane >> 4;
  int gpx = wid * 16 + col;           // tile-local pixel 0..63
  int py = gpx >> 3, px_ = gpx & 7;

  f32x4 acc[2];
  acc[0] = (f32x4){0.f, 0.f, 0.f, 0.f};
  acc[1] = (f32x4){0.f, 0.f, 0.f, 0.f};

#pragma unroll
  for (int tap = 0; tap < 9; ++tap) {
    int dy = tap / 3 - 1;
    int dx = tap - (tap / 3) * 3 - 1;
    int pos = (py + 1 + dy) * 10 + (px_ + 1 + dx);
    int pbase = pos * 384;
    int psw = (pos & 7) << 4;
#pragma unroll
    for (int cs = 0; cs < 6; ++cs) {
      short8v bfrag = *(const short8v*)(sb + pbase + ((cs * 64 + kg * 16) ^ psw));
      const unsigned short* wrow = w2b + tap * C_ + cs * 32 + kg * 8;
      short8v a0 = *(const short8v*)(wrow + (size_t)col * K2);
      short8v a1 = *(const short8v*)(wrow + (size_t)(16 + col) * K2);
      acc[0] = __builtin_amdgcn_mfma_f32_16x16x32_bf16(a0, bfrag, acc[0], 0, 0, 0);
      acc[1] = __builtin_amdgcn_mfma_f32_16x16x32_bf16(a1, bfrag, acc[1], 0, 0, 0);
    }
  }

#pragma unroll
  for (int mf = 0; mf < 2; ++mf) {
#pragma unroll
    for (int reg = 0; reg < 4; ++reg) {
      int o = mf * 16 + kg * 4 + reg;
      if (o < NOFF) {
        float v = acc[mf][reg];
        v = fminf(fmaxf(v, -1.f), 1.f);
        offp[((size_t)b * NOFF + o) * HW_ + (h0 + py) * W_ + w0 + px_] = v;
      }
    }
  }
}

// ------- K3: deform sample + dcn; tap-split 3-way, bf16 partial buffers ---
__global__ __launch_bounds__(TPB) void k_deform7(const unsigned short* __restrict__ xt,
                                                 const float* __restrict__ offp,
                                                 const float* __restrict__ dcn,
                                                 unsigned short* __restrict__ y1p) {
  __shared__ __align__(16) float dcnT[3 * C_];
  int tid = threadIdx.x;
  int kt0 = blockIdx.y * 3;
  for (int t = tid; t < 3 * C_; t += TPB) {
    int k = t / C_, c = t - k * C_;
    dcnT[t] = dcn[c * 9 + kt0 + k];
  }
  __syncthreads();
  y1p += (size_t)blockIdx.y * NPIX * C_;

  int px = blockIdx.x * 16 + (tid >> 4);
  int lg = tid & 15;
  int b = px / HW_;
  int hw = px - b * HW_;
  int h = hw / W_;
  int w = hw - h * W_;
  const float* op = offp + (size_t)b * NOFF * HW_ + hw;
  int pb = b * HW_;

  float acc[12];
#pragma unroll
  for (int j = 0; j < 12; ++j) acc[j] = 0.f;

#pragma unroll
  for (int k3 = 0; k3 < 3; ++k3) {
    int tap = kt0 + k3;
    int t3 = tap / 3;
    int ky = t3 - 1;
    int kx = tap - t3 * 3 - 1;
    float dy = op[(2 * tap) * HW_];
    float dx = op[(2 * tap + 1) * HW_];
    float ys = (float)(h + ky) + dy;
    float xs = (float)(w + kx) + dx;
    float y0f = floorf(ys), x0f = floorf(xs);
    float ty = ys - y0f, tx = xs - x0f;
    int y0 = (int)y0f, x0 = (int)x0f;
    int y1 = y0 + 1, x1 = x0 + 1;
    float fy0 = ((unsigned)y0 < (unsigned)H_) ? 1.f : 0.f;
    float fy1 = ((unsigned)y1 < (unsigned)H_) ? 1.f : 0.f;
    float fx0 = ((unsigned)x0 < (unsigned)W_) ? 1.f : 0.f;
    float fx1 = ((unsigned)x1 < (unsigned)W_) ? 1.f : 0.f;
    int y0c = y0 < 0 ? 0 : (y0 > H_ - 1 ? H_ - 1 : y0);
    int y1c = y1 < 0 ? 0 : (y1 > H_ - 1 ? H_ - 1 : y1);
    int x0c = x0 < 0 ? 0 : (x0 > W_ - 1 ? W_ - 1 : x0);
    int x1c = x1 < 0 ? 0 : (x1 > W_ - 1 ? W_ - 1 : x1);
    float omty = 1.f - ty, omtx = 1.f - tx;
    float w00 = omty * omtx * fy0 * fx0;
    float w01 = omty * tx * fy0 * fx1;
    float w10 = ty * omtx * fy1 * fx0;
    float w11 = ty * tx * fy1 * fx1;
    int r0 = (pb + y0c * W_) * C_;
    int r1 = (pb + y1c * W_) * C_;
    int p00 = r0 + x0c * C_;
    int p01 = r0 + x1c * C_;
    int p10 = r1 + x0c * C_;
    int p11 = r1 + x1c * C_;
#pragma unroll
    for (int rep = 0; rep < 3; ++rep) {
      int c0 = lg * 4 + rep * 64;
      uint2 u00 = *(const uint2*)(xt + p00 + c0);
      uint2 u01 = *(const uint2*)(xt + p01 + c0);
      uint2 u10 = *(const uint2*)(xt + p10 + c0);
      uint2 u11 = *(const uint2*)(xt + p11 + c0);
      f32x4 dw = *(const f32x4*)&dcnT[k3 * C_ + c0];
      float s0 = w00 * bflo(u00.x) + w01 * bflo(u01.x) + w10 * bflo(u10.x) + w11 * bflo(u11.x);
      float s1 = w00 * bfhi(u00.x) + w01 * bfhi(u01.x) + w10 * bfhi(u10.x) + w11 * bfhi(u11.x);
      float s2 = w00 * bflo(u00.y) + w01 * bflo(u01.y) + w10 * bflo(u10.y) + w11 * bflo(u11.y);
      float s3 = w00 * bfhi(u00.y) + w01 * bfhi(u01.y) + w10 * bfhi(u10.y) + w11 * bfhi(u11.y);
      acc[rep * 4 + 0] += s0 * dw.x;
      acc[rep * 4 + 1] += s1 * dw.y;
      acc[rep * 4 + 2] += s2 * dw.z;
      acc[rep * 4 + 3] += s3 * dw.w;
    }
  }

  int ob = px * C_ + lg * 4;
#pragma unroll
  for (int rep = 0; rep < 3; ++rep) {
    uint2 pk;
    pk.x = (unsigned)f2bf(acc[rep * 4 + 0]) | ((unsigned)f2bf(acc[rep * 4 + 1]) << 16);
    pk.y = (unsigned)f2bf(acc[rep * 4 + 2]) | ((unsigned)f2bf(acc[rep * 4 + 3]) << 16);
    *(uint2*)(y1p + ob + rep * 64) = pk;
  }
}

// ---- K4: one block = 64 px x ALL 384 O; bf16 partials read once ----------
__global__ __launch_bounds__(TPB) void k_gemm3b(const unsigned short* __restrict__ y1p,
                                                const unsigned short* __restrict__ wtb,
                                                float* __restrict__ out) {
  __shared__ __align__(16) unsigned short bsm[64 * 192];  // 24 KB
  int tid = threadIdx.x;
  int n0 = blockIdx.x * 64;

  const unsigned short* s0 = y1p + (size_t)n0 * C_;
  const unsigned short* s1 = s0 + (size_t)NPIX * C_;
  const unsigned short* s2 = s1 + (size_t)NPIX * C_;
  char* sbase = (char*)bsm;
#pragma unroll
  for (int i = 0; i < 12; ++i) {
    int u = i * TPB + tid;            // 8B-dst unit: 64 rows x 48 units
    int row = u / 48;
    int cu = u - row * 48;
    int so = row * 192 + cu * 4;
    uint2 a = *(const uint2*)(s0 + so);
    uint2 b4 = *(const uint2*)(s1 + so);
    uint2 c4 = *(const uint2*)(s2 + so);
    float v0 = bflo(a.x) + bflo(b4.x) + bflo(c4.x);
    float v1 = bfhi(a.x) + bfhi(b4.x) + bfhi(c4.x);
    float v2 = bflo(a.y) + bflo(b4.y) + bflo(c4.y);
    float v3 = bfhi(a.y) + bfhi(b4.y) + bfhi(c4.y);
    uint2 pk;
    pk.x = (unsigned)f2bf(v0) | ((unsigned)f2bf(v1) << 16);
    pk.y = (unsigned)f2bf(v2) | ((unsigned)f2bf(v3) << 16);
    *(uint2*)(sbase + row * 384 + ((cu * 8) ^ ((row & 7) << 4))) = pk;
  }
  __syncthreads();

  int wid = tid >> 6;
  int lane = tid & 63;
  int col = lane & 15;
  int kg = lane >> 4;
  int wr = wid >> 1;                  // O-half (0,1)
  int wc = wid & 1;                   // px-half (0,1)

#pragma unroll 1
  for (int m0 = 0; m0 < O_; m0 += 64) {
    f32x4 acc[2][2];
#pragma unroll
    for (int mf = 0; mf < 2; ++mf)
#pragma unroll
      for (int nf = 0; nf < 2; ++nf) acc[mf][nf] = (f32x4){0.f, 0.f, 0.f, 0.f};

#pragma unroll
    for (int k0 = 0; k0 < C_; k0 += 32) {
      short8v a[2], bfr[2];
#pragma unroll
      for (int mf = 0; mf < 2; ++mf)
        a[mf] = *(const short8v*)(wtb + (m0 + wr * 32 + mf * 16 + col) * C_ + k0 + kg * 8);
#pragma unroll
      for (int nf = 0; nf < 2; ++nf) {
        int brow = wc * 32 + nf * 16 + col;
        int kb = (k0 + kg * 8) * 2;
        bfr[nf] = *(const short8v*)(sbase + brow * 384 + (kb ^ ((brow & 7) << 4)));
      }
#pragma unroll
      for (int mf = 0; mf < 2; ++mf)
#pragma unroll
        for (int nf = 0; nf < 2; ++nf)
          acc[mf][nf] = __builtin_amdgcn_mfma_f32_16x16x32_bf16(a[mf], bfr[nf], acc[mf][nf], 0, 0, 0);
    }

#pragma unroll
    for (int mf = 0; mf < 2; ++mf) {
#pragma unroll
      for (int nf = 0; nf < 2; ++nf) {
        int p = n0 + wc * 32 + nf * 16 + col;
        int bb = p / HW_;
        int hw = p - bb * HW_;
#pragma unroll
        for (int reg = 0; reg < 4; ++reg) {
          int o = m0 + wr * 32 + mf * 16 + kg * 4 + reg;
          float a = acc[mf][nf][reg];
          float r = a * fminf(fmaxf(a + 3.f, 0.f), 6.f) * (1.f / 6.f);
          out[((size_t)bb * O_ + o) * HW_ + hw] = r;
        }
      }
    }
  }
}

extern "C" void kernel_launch(void* const* d_in, const int* in_sizes, int n_in,
                              void* d_out, int out_size, void* d_ws, size_t ws_size,
                              hipStream_t stream) {
  const float* x = (const float*)d_in[0];
  const float* og_dw = (const float*)d_in[1];
  const float* og_pw = (const float*)d_in[2];
  const float* dcn_w = (const float*)d_in[3];
  const float* pw_w = (const float*)d_in[4];
  float* out = (float*)d_out;

  float* ws = (float*)d_ws;
  float* offp = ws;                                      // B*18*HW fp32
  unsigned short* y1p = (unsigned short*)(offp + (size_t)B_ * NOFF * HW_);  // 3*NPIX*C bf16
  unsigned short* wtb = y1p + 3 * (size_t)NPIX * C_;     // O*C bf16
  unsigned short* x_t = wtb + (size_t)O_ * C_;           // NPIX*C bf16
  unsigned short* w2b = x_t + (size_t)NPIX * C_;         // 32*1728 bf16

  k_wb<<<(O_ * C_ + TPB - 1) / TPB, TPB, 0, stream>>>(pw_w, wtb);
  k_w2<<<(32 * K2 + TPB - 1) / TPB, TPB, 0, stream>>>(og_dw, og_pw, w2b);
  k_xt<<<dim3(HW_ / 64, B_), TPB, 0, stream>>>(x, x_t);
  k_off<<<dim3(W_ / 8, H_ / 8, B_), TPB, 0, stream>>>(x_t, w2b, offp);
  k_deform7<<<dim3(NPIX / 16, 3), TPB, 0, stream>>>(x_t, offp, dcn_w, y1p);
  k_gemm3b<<<NPIX / 64, TPB, 0, stream>>>(y1p, wtb, out);
}

// Round 11
// 99.462 us; speedup vs baseline: 1.3560x; 1.1103x over previous
//
#include <hip/hip_runtime.h>

#define TPB 256
constexpr int B_ = 8, C_ = 192, H_ = 56, W_ = 56, O_ = 384;
constexpr int HW_ = H_ * W_;          // 3136
constexpr int NOFF = 18;              // 9 taps * 2 (dy,dx)
constexpr int NPIX = B_ * HW_;        // 25088 = 196 * 128
constexpr int K2 = 9 * C_;            // 1728 combined-conv K

typedef __attribute__((ext_vector_type(8))) short short8v;
typedef __attribute__((ext_vector_type(4))) float f32x4;

__device__ inline unsigned short f2bf(float f) {
  unsigned u = __builtin_bit_cast(unsigned, f);
  unsigned r = (u + 0x7fffu + ((u >> 16) & 1u)) >> 16;
  return (unsigned short)r;
}
__device__ inline float bflo(unsigned u) {
  return __builtin_bit_cast(float, u << 16);
}
__device__ inline float bfhi(unsigned u) {
  return __builtin_bit_cast(float, u & 0xffff0000u);
}

// ---- K_PREP: wtb = bf16(pw_w); W2[o][tap*192+c] = og_pw[o,c]*og_dw[c,tap] -
__global__ __launch_bounds__(TPB) void k_prep(const float* __restrict__ og_dw,
                                              const float* __restrict__ og_pw,
                                              const float* __restrict__ pw,
                                              unsigned short* __restrict__ wtb,
                                              unsigned short* __restrict__ w2b) {
  int i = blockIdx.x * TPB + threadIdx.x;
  if (i < O_ * C_) wtb[i] = f2bf(pw[i]);
  int j = i - O_ * C_;
  if (j >= 0 && j < 32 * K2) {
    int o = j / K2, k = j - o * K2;
    int tap = k / C_, c = k - tap * C_;
    float v = 0.f;
    if (o < NOFF) v = og_pw[o * C_ + c] * og_dw[c * 9 + tap];
    w2b[j] = f2bf(v);
  }
}

// ---------------- K_XT: x[b][c][h][w] fp32 -> x_t[b][hw][c] bf16 ----------
__global__ __launch_bounds__(TPB) void k_xt(const float* __restrict__ x,
                                            unsigned short* __restrict__ xt) {
  __shared__ unsigned short tile[64 * 198];
  int tid = threadIdx.x;
  int P0 = blockIdx.x * 64;
  int b = blockIdx.y;
#pragma unroll
  for (int i = 0; i < 48; ++i) {
    int idx = i * TPB + tid;
    int px = idx & 63;
    int c = idx >> 6;
    float v = x[((size_t)(b * C_ + c)) * HW_ + P0 + px];
    tile[px * 198 + c] = f2bf(v);
  }
  __syncthreads();
  unsigned* xtu = (unsigned*)xt;
#pragma unroll
  for (int i = 0; i < 24; ++i) {
    int d = i * TPB + tid;            // dword index in 64*96
    int px = d / 96;
    int c2 = d - px * 96;
    unsigned v = *(const unsigned*)&tile[px * 198 + c2 * 2];
    xtu[((size_t)b * HW_ + P0 + px) * 96 + c2] = v;
  }
}

// ---- K_OFF2: offset conv, K-split by tap-row (dy band); f32 partials -----
// block = 8x8 px tile x (b, s); halo = 8 rows (shifted by dy) x 10 cols.
__global__ __launch_bounds__(TPB) void k_off2(const unsigned short* __restrict__ xt,
                                              const unsigned short* __restrict__ w2b,
                                              float* __restrict__ offp3) {
  __shared__ __align__(16) unsigned short hal[80 * 192];  // 30.7 KB
  int tid = threadIdx.x;
  int w0 = blockIdx.x * 8;
  int h0 = blockIdx.y * 8;
  int bz = blockIdx.z;
  int b = bz / 3;
  int s = bz - b * 3;                 // tap-row split; dy = s-1
  int dy = s - 1;

  char* sb = (char*)hal;
  const uint4* xu4 = (const uint4*)xt;  // 16B = 8ch; 24 units per pixel
#pragma unroll
  for (int i = 0; i < 8; ++i) {
    int u = i * TPB + tid;            // 80 pos x 24 uint4 = 1920
    if (u < 1920) {
      int pos = u / 24, c4 = u - pos * 24;
      int ry = pos / 10;
      int gy = h0 + ry + dy;
      int gx = w0 - 1 + (pos - ry * 10);
      uint4 v = {0u, 0u, 0u, 0u};
      if ((unsigned)gy < (unsigned)H_ && (unsigned)gx < (unsigned)W_)
        v = xu4[((size_t)b * HW_ + gy * W_ + gx) * 24 + c4];
      *(uint4*)(sb + pos * 384 + ((c4 * 16) ^ ((pos & 7) << 4))) = v;
    }
  }
  __syncthreads();

  int wid = tid >> 6;
  int lane = tid & 63;
  int col = lane & 15;
  int kg = lane >> 4;
  int gpx = wid * 16 + col;           // tile-local pixel 0..63
  int py = gpx >> 3, px_ = gpx & 7;

  f32x4 acc0 = (f32x4){0.f, 0.f, 0.f, 0.f};
  f32x4 acc1 = (f32x4){0.f, 0.f, 0.f, 0.f};

#pragma unroll
  for (int j = 0; j < 3; ++j) {       // dx = j-1; tap = 3s+j
    int tap = 3 * s + j;
    int pos = py * 10 + px_ + j;
    int pbase = pos * 384;
    int psw = (pos & 7) << 4;
    const unsigned short* wrow = w2b + tap * C_ + kg * 8;
#pragma unroll
    for (int cs = 0; cs < 6; ++cs) {
      short8v bfrag = *(const short8v*)(sb + pbase + ((cs * 64 + kg * 16) ^ psw));
      short8v a0 = *(const short8v*)(wrow + cs * 32 + (size_t)col * K2);
      short8v a1 = *(const short8v*)(wrow + cs * 32 + (size_t)(16 + col) * K2);
      acc0 = __builtin_amdgcn_mfma_f32_16x16x32_bf16(a0, bfrag, acc0, 0, 0, 0);
      acc1 = __builtin_amdgcn_mfma_f32_16x16x32_bf16(a1, bfrag, acc1, 0, 0, 0);
    }
  }

  float* ob = offp3 + (size_t)(s * B_ + b) * NOFF * HW_ + (h0 + py) * W_ + w0 + px_;
#pragma unroll
  for (int reg = 0; reg < 4; ++reg) {
    int o0 = kg * 4 + reg;            // 0..15, always < 18
    ob[(size_t)o0 * HW_] = acc0[reg];
    int o1 = 16 + kg * 4 + reg;       // valid only for 16,17
    if (o1 < NOFF) ob[(size_t)o1 * HW_] = acc1[reg];
  }
}

// ---- K3: deform sample + dcn; tap-split 3-way; offsets = sum of partials -
__global__ __launch_bounds__(TPB) void k_deform8(const unsigned short* __restrict__ xt,
                                                 const float* __restrict__ offp3,
                                                 const float* __restrict__ dcn,
                                                 unsigned short* __restrict__ y1p) {
  __shared__ __align__(16) float dcnT[3 * C_];
  int tid = threadIdx.x;
  int kt0 = blockIdx.y * 3;
  for (int t = tid; t < 3 * C_; t += TPB) {
    int k = t / C_, c = t - k * C_;
    dcnT[t] = dcn[c * 9 + kt0 + k];
  }
  __syncthreads();
  y1p += (size_t)blockIdx.y * NPIX * C_;

  int px = blockIdx.x * 16 + (tid >> 4);
  int lg = tid & 15;
  int b = px / HW_;
  int hw = px - b * HW_;
  int h = hw / W_;
  int w = hw - h * W_;
  const float* p0 = offp3 + (size_t)(0 * B_ + b) * NOFF * HW_ + hw;
  const float* p1 = offp3 + (size_t)(1 * B_ + b) * NOFF * HW_ + hw;
  const float* p2 = offp3 + (size_t)(2 * B_ + b) * NOFF * HW_ + hw;
  int pb = b * HW_;

  float acc[12];
#pragma unroll
  for (int j = 0; j < 12; ++j) acc[j] = 0.f;

#pragma unroll
  for (int k3 = 0; k3 < 3; ++k3) {
    int tap = kt0 + k3;
    int t3 = tap / 3;
    int ky = t3 - 1;
    int kx = tap - t3 * 3 - 1;
    size_t ody = (size_t)(2 * tap) * HW_;
    size_t odx = (size_t)(2 * tap + 1) * HW_;
    float dyv = p0[ody] + p1[ody] + p2[ody];
    float dxv = p0[odx] + p1[odx] + p2[odx];
    dyv = fminf(fmaxf(dyv, -1.f), 1.f);
    dxv = fminf(fmaxf(dxv, -1.f), 1.f);
    float ys = (float)(h + ky) + dyv;
    float xs = (float)(w + kx) + dxv;
    float y0f = floorf(ys), x0f = floorf(xs);
    float ty = ys - y0f, tx = xs - x0f;
    int y0 = (int)y0f, x0 = (int)x0f;
    int y1 = y0 + 1, x1 = x0 + 1;
    float fy0 = ((unsigned)y0 < (unsigned)H_) ? 1.f : 0.f;
    float fy1 = ((unsigned)y1 < (unsigned)H_) ? 1.f : 0.f;
    float fx0 = ((unsigned)x0 < (unsigned)W_) ? 1.f : 0.f;
    float fx1 = ((unsigned)x1 < (unsigned)W_) ? 1.f : 0.f;
    int y0c = y0 < 0 ? 0 : (y0 > H_ - 1 ? H_ - 1 : y0);
    int y1c = y1 < 0 ? 0 : (y1 > H_ - 1 ? H_ - 1 : y1);
    int x0c = x0 < 0 ? 0 : (x0 > W_ - 1 ? W_ - 1 : x0);
    int x1c = x1 < 0 ? 0 : (x1 > W_ - 1 ? W_ - 1 : x1);
    float omty = 1.f - ty, omtx = 1.f - tx;
    float w00 = omty * omtx * fy0 * fx0;
    float w01 = omty * tx * fy0 * fx1;
    float w10 = ty * omtx * fy1 * fx0;
    float w11 = ty * tx * fy1 * fx1;
    int r0 = (pb + y0c * W_) * C_;
    int r1 = (pb + y1c * W_) * C_;
    int p00 = r0 + x0c * C_;
    int p01 = r0 + x1c * C_;
    int p10 = r1 + x0c * C_;
    int p11 = r1 + x1c * C_;
#pragma unroll
    for (int rep = 0; rep < 3; ++rep) {
      int c0 = lg * 4 + rep * 64;
      uint2 u00 = *(const uint2*)(xt + p00 + c0);
      uint2 u01 = *(const uint2*)(xt + p01 + c0);
      uint2 u10 = *(const uint2*)(xt + p10 + c0);
      uint2 u11 = *(const uint2*)(xt + p11 + c0);
      f32x4 dw = *(const f32x4*)&dcnT[k3 * C_ + c0];
      float s0 = w00 * bflo(u00.x) + w01 * bflo(u01.x) + w10 * bflo(u10.x) + w11 * bflo(u11.x);
      float s1 = w00 * bfhi(u00.x) + w01 * bfhi(u01.x) + w10 * bfhi(u10.x) + w11 * bfhi(u11.x);
      float s2 = w00 * bflo(u00.y) + w01 * bflo(u01.y) + w10 * bflo(u10.y) + w11 * bflo(u11.y);
      float s3 = w00 * bfhi(u00.y) + w01 * bfhi(u01.y) + w10 * bfhi(u10.y) + w11 * bfhi(u11.y);
      acc[rep * 4 + 0] += s0 * dw.x;
      acc[rep * 4 + 1] += s1 * dw.y;
      acc[rep * 4 + 2] += s2 * dw.z;
      acc[rep * 4 + 3] += s3 * dw.w;
    }
  }

  int ob = px * C_ + lg * 4;
#pragma unroll
  for (int rep = 0; rep < 3; ++rep) {
    uint2 pk;
    pk.x = (unsigned)f2bf(acc[rep * 4 + 0]) | ((unsigned)f2bf(acc[rep * 4 + 1]) << 16);
    pk.y = (unsigned)f2bf(acc[rep * 4 + 2]) | ((unsigned)f2bf(acc[rep * 4 + 3]) << 16);
    *(uint2*)(y1p + ob + rep * 64) = pk;
  }
}

// ---- K4: one block = 64 px x ALL 384 O; bf16 partials read once ----------
__global__ __launch_bounds__(TPB) void k_gemm3b(const unsigned short* __restrict__ y1p,
                                                const unsigned short* __restrict__ wtb,
                                                float* __restrict__ out) {
  __shared__ __align__(16) unsigned short bsm[64 * 192];  // 24 KB
  int tid = threadIdx.x;
  int n0 = blockIdx.x * 64;

  const unsigned short* s0 = y1p + (size_t)n0 * C_;
  const unsigned short* s1 = s0 + (size_t)NPIX * C_;
  const unsigned short* s2 = s1 + (size_t)NPIX * C_;
  char* sbase = (char*)bsm;
#pragma unroll
  for (int i = 0; i < 12; ++i) {
    int u = i * TPB + tid;            // 8B-dst unit: 64 rows x 48 units
    int row = u / 48;
    int cu = u - row * 48;
    int so = row * 192 + cu * 4;
    uint2 a = *(const uint2*)(s0 + so);
    uint2 b4 = *(const uint2*)(s1 + so);
    uint2 c4 = *(const uint2*)(s2 + so);
    float v0 = bflo(a.x) + bflo(b4.x) + bflo(c4.x);
    float v1 = bfhi(a.x) + bfhi(b4.x) + bfhi(c4.x);
    float v2 = bflo(a.y) + bflo(b4.y) + bflo(c4.y);
    float v3 = bfhi(a.y) + bfhi(b4.y) + bfhi(c4.y);
    uint2 pk;
    pk.x = (unsigned)f2bf(v0) | ((unsigned)f2bf(v1) << 16);
    pk.y = (unsigned)f2bf(v2) | ((unsigned)f2bf(v3) << 16);
    *(uint2*)(sbase + row * 384 + ((cu * 8) ^ ((row & 7) << 4))) = pk;
  }
  __syncthreads();

  int wid = tid >> 6;
  int lane = tid & 63;
  int col = lane & 15;
  int kg = lane >> 4;
  int wr = wid >> 1;                  // O-half (0,1)
  int wc = wid & 1;                   // px-half (0,1)

#pragma unroll 1
  for (int m0 = 0; m0 < O_; m0 += 64) {
    f32x4 acc[2][2];
#pragma unroll
    for (int mf = 0; mf < 2; ++mf)
#pragma unroll
      for (int nf = 0; nf < 2; ++nf) acc[mf][nf] = (f32x4){0.f, 0.f, 0.f, 0.f};

#pragma unroll
    for (int k0 = 0; k0 < C_; k0 += 32) {
      short8v a[2], bfr[2];
#pragma unroll
      for (int mf = 0; mf < 2; ++mf)
        a[mf] = *(const short8v*)(wtb + (m0 + wr * 32 + mf * 16 + col) * C_ + k0 + kg * 8);
#pragma unroll
      for (int nf = 0; nf < 2; ++nf) {
        int brow = wc * 32 + nf * 16 + col;
        int kb = (k0 + kg * 8) * 2;
        bfr[nf] = *(const short8v*)(sbase + brow * 384 + (kb ^ ((brow & 7) << 4)));
      }
#pragma unroll
      for (int mf = 0; mf < 2; ++mf)
#pragma unroll
        for (int nf = 0; nf < 2; ++nf)
          acc[mf][nf] = __builtin_amdgcn_mfma_f32_16x16x32_bf16(a[mf], bfr[nf], acc[mf][nf], 0, 0, 0);
    }

#pragma unroll
    for (int mf = 0; mf < 2; ++mf) {
#pragma unroll
      for (int nf = 0; nf < 2; ++nf) {
        int p = n0 + wc * 32 + nf * 16 + col;
        int bb = p / HW_;
        int hw = p - bb * HW_;
#pragma unroll
        for (int reg = 0; reg < 4; ++reg) {
          int o = m0 + wr * 32 + mf * 16 + kg * 4 + reg;
          float a = acc[mf][nf][reg];
          float r = a * fminf(fmaxf(a + 3.f, 0.f), 6.f) * (1.f / 6.f);
          out[((size_t)bb * O_ + o) * HW_ + hw] = r;
        }
      }
    }
  }
}

extern "C" void kernel_launch(void* const* d_in, const int* in_sizes, int n_in,
                              void* d_out, int out_size, void* d_ws, size_t ws_size,
                              hipStream_t stream) {
  const float* x = (const float*)d_in[0];
  const float* og_dw = (const float*)d_in[1];
  const float* og_pw = (const float*)d_in[2];
  const float* dcn_w = (const float*)d_in[3];
  const float* pw_w = (const float*)d_in[4];
  float* out = (float*)d_out;

  float* ws = (float*)d_ws;
  float* offp3 = ws;                                     // 3*B*18*HW f32
  unsigned short* y1p = (unsigned short*)(offp3 + 3 * (size_t)B_ * NOFF * HW_);
  unsigned short* wtb = y1p + 3 * (size_t)NPIX * C_;     // O*C bf16
  unsigned short* x_t = wtb + (size_t)O_ * C_;           // NPIX*C bf16
  unsigned short* w2b = x_t + (size_t)NPIX * C_;         // 32*1728 bf16

  k_prep<<<(O_ * C_ + 32 * K2 + TPB - 1) / TPB, TPB, 0, stream>>>(og_dw, og_pw, pw_w, wtb, w2b);
  k_xt<<<dim3(HW_ / 64, B_), TPB, 0, stream>>>(x, x_t);
  k_off2<<<dim3(W_ / 8, H_ / 8, B_ * 3), TPB, 0, stream>>>(x_t, w2b, offp3);
  k_deform8<<<dim3(NPIX / 16, 3), TPB, 0, stream>>>(x_t, offp3, dcn_w, y1p);
  k_gemm3b<<<NPIX / 64, TPB, 0, stream>>>(y1p, wtb, out);
}

// Round 12
// 98.373 us; speedup vs baseline: 1.3710x; 1.0111x over previous
//
#include <hip/hip_runtime.h>

#define TPB 256
constexpr int B_ = 8, C_ = 192, H_ = 56, W_ = 56, O_ = 384;
constexpr int HW_ = H_ * W_;          // 3136
constexpr int NOFF = 18;              // 9 taps * 2 (dy,dx)
constexpr int NPIX = B_ * HW_;        // 25088 = 196 * 128
constexpr int K2 = 9 * C_;            // 1728 combined-conv K

typedef __attribute__((ext_vector_type(8))) short short8v;
typedef __attribute__((ext_vector_type(4))) float f32x4;

__device__ inline unsigned short f2bf(float f) {
  unsigned u = __builtin_bit_cast(unsigned, f);
  unsigned r = (u + 0x7fffu + ((u >> 16) & 1u)) >> 16;
  return (unsigned short)r;
}
__device__ inline float bflo(unsigned u) {
  return __builtin_bit_cast(float, u << 16);
}
__device__ inline float bfhi(unsigned u) {
  return __builtin_bit_cast(float, u & 0xffff0000u);
}

// ---- K_PREP: wtb = bf16(pw_w); W2[o][tap*192+c] = og_pw[o,c]*og_dw[c,tap] -
__global__ __launch_bounds__(TPB) void k_prep(const float* __restrict__ og_dw,
                                              const float* __restrict__ og_pw,
                                              const float* __restrict__ pw,
                                              unsigned short* __restrict__ wtb,
                                              unsigned short* __restrict__ w2b) {
  int i = blockIdx.x * TPB + threadIdx.x;
  if (i < O_ * C_) wtb[i] = f2bf(pw[i]);
  int j = i - O_ * C_;
  if (j >= 0 && j < 32 * K2) {
    int o = j / K2, k = j - o * K2;
    int tap = k / C_, c = k - tap * C_;
    float v = 0.f;
    if (o < NOFF) v = og_pw[o * C_ + c] * og_dw[c * 9 + tap];
    w2b[j] = f2bf(v);
  }
}

// ---------------- K_XT: x[b][c][h][w] fp32 -> x_t[b][hw][c] bf16 ----------
__global__ __launch_bounds__(TPB) void k_xt(const float* __restrict__ x,
                                            unsigned short* __restrict__ xt) {
  __shared__ unsigned short tile[64 * 198];
  int tid = threadIdx.x;
  int P0 = blockIdx.x * 64;
  int b = blockIdx.y;
#pragma unroll
  for (int i = 0; i < 48; ++i) {
    int idx = i * TPB + tid;
    int px = idx & 63;
    int c = idx >> 6;
    float v = x[((size_t)(b * C_ + c)) * HW_ + P0 + px];
    tile[px * 198 + c] = f2bf(v);
  }
  __syncthreads();
  unsigned* xtu = (unsigned*)xt;
#pragma unroll
  for (int i = 0; i < 24; ++i) {
    int d = i * TPB + tid;            // dword index in 64*96
    int px = d / 96;
    int c2 = d - px * 96;
    unsigned v = *(const unsigned*)&tile[px * 198 + c2 * 2];
    xtu[((size_t)b * HW_ + P0 + px) * 96 + c2] = v;
  }
}

// ---- K_OFF2: offset conv, K-split by tap-row (dy band); f32 partials -----
__global__ __launch_bounds__(TPB) void k_off2(const unsigned short* __restrict__ xt,
                                              const unsigned short* __restrict__ w2b,
                                              float* __restrict__ offp3) {
  __shared__ __align__(16) unsigned short hal[80 * 192];  // 30.7 KB
  int tid = threadIdx.x;
  int w0 = blockIdx.x * 8;
  int h0 = blockIdx.y * 8;
  int bz = blockIdx.z;
  int b = bz / 3;
  int s = bz - b * 3;                 // tap-row split; dy = s-1
  int dy = s - 1;

  char* sb = (char*)hal;
  const uint4* xu4 = (const uint4*)xt;  // 16B = 8ch; 24 units per pixel
#pragma unroll
  for (int i = 0; i < 8; ++i) {
    int u = i * TPB + tid;            // 80 pos x 24 uint4 = 1920
    if (u < 1920) {
      int pos = u / 24, c4 = u - pos * 24;
      int ry = pos / 10;
      int gy = h0 + ry + dy;
      int gx = w0 - 1 + (pos - ry * 10);
      uint4 v = {0u, 0u, 0u, 0u};
      if ((unsigned)gy < (unsigned)H_ && (unsigned)gx < (unsigned)W_)
        v = xu4[((size_t)b * HW_ + gy * W_ + gx) * 24 + c4];
      *(uint4*)(sb + pos * 384 + ((c4 * 16) ^ ((pos & 7) << 4))) = v;
    }
  }
  __syncthreads();

  int wid = tid >> 6;
  int lane = tid & 63;
  int col = lane & 15;
  int kg = lane >> 4;
  int gpx = wid * 16 + col;           // tile-local pixel 0..63
  int py = gpx >> 3, px_ = gpx & 7;

  f32x4 acc0 = (f32x4){0.f, 0.f, 0.f, 0.f};
  f32x4 acc1 = (f32x4){0.f, 0.f, 0.f, 0.f};

#pragma unroll
  for (int j = 0; j < 3; ++j) {       // dx = j-1; tap = 3s+j
    int tap = 3 * s + j;
    int pos = py * 10 + px_ + j;
    int pbase = pos * 384;
    int psw = (pos & 7) << 4;
    const unsigned short* wrow = w2b + tap * C_ + kg * 8;
#pragma unroll
    for (int cs = 0; cs < 6; ++cs) {
      short8v bfrag = *(const short8v*)(sb + pbase + ((cs * 64 + kg * 16) ^ psw));
      short8v a0 = *(const short8v*)(wrow + cs * 32 + (size_t)col * K2);
      short8v a1 = *(const short8v*)(wrow + cs * 32 + (size_t)(16 + col) * K2);
      acc0 = __builtin_amdgcn_mfma_f32_16x16x32_bf16(a0, bfrag, acc0, 0, 0, 0);
      acc1 = __builtin_amdgcn_mfma_f32_16x16x32_bf16(a1, bfrag, acc1, 0, 0, 0);
    }
  }

  float* ob = offp3 + (size_t)(s * B_ + b) * NOFF * HW_ + (h0 + py) * W_ + w0 + px_;
#pragma unroll
  for (int reg = 0; reg < 4; ++reg) {
    int o0 = kg * 4 + reg;            // 0..15, always < 18
    ob[(size_t)o0 * HW_] = acc0[reg];
    int o1 = 16 + kg * 4 + reg;       // valid only for 16,17
    if (o1 < NOFF) ob[(size_t)o1 * HW_] = acc1[reg];
  }
}

// ---- K3: deform+dcn, LDS-halo version. block = 4x4 px, all 9 taps -------
// Clip(|off|<=1) => all corners within 9x9 halo rows h0-2..h0+6.
// Zero-filled OOB == reference valid-mask semantics.
__global__ __launch_bounds__(TPB) void k_deform9(const unsigned short* __restrict__ xt,
                                                 const float* __restrict__ offp3,
                                                 const float* __restrict__ dcn,
                                                 unsigned short* __restrict__ y1t) {
  __shared__ __align__(16) unsigned short hal[81 * 192];  // 31.1 KB
  __shared__ __align__(16) float dcnT[9 * C_];            // 6.9 KB
  int tid = threadIdx.x;
  int tile = blockIdx.x;
  int b = blockIdx.y;
  int h0 = (tile / 14) * 4;
  int w0 = (tile - (tile / 14) * 14) * 4;

  for (int t = tid; t < 9 * C_; t += TPB) {
    int k = t / C_, c = t - k * C_;
    dcnT[t] = dcn[c * 9 + k];
  }
  char* sb = (char*)hal;
  const uint4* xu4 = (const uint4*)xt;
#pragma unroll
  for (int i = 0; i < 8; ++i) {
    int u = i * TPB + tid;            // 81 pos x 24 uint4 = 1944
    if (u < 1944) {
      int pos = u / 24, c4 = u - pos * 24;
      int ly = pos / 9, lx = pos - ly * 9;
      int gy = h0 - 2 + ly, gx = w0 - 2 + lx;
      uint4 v = {0u, 0u, 0u, 0u};
      if ((unsigned)gy < (unsigned)H_ && (unsigned)gx < (unsigned)W_)
        v = xu4[((size_t)b * HW_ + gy * W_ + gx) * 24 + c4];
      *(uint4*)(sb + pos * 384 + ((c4 * 16) ^ ((pos & 7) << 4))) = v;
    }
  }
  __syncthreads();

  int pl = tid >> 4;                  // 0..15: local pixel
  int lg = tid & 15;
  int py = pl >> 2, px_ = pl & 3;
  int h = h0 + py, w = w0 + px_;
  int hw = h * W_ + w;
  const float* p0 = offp3 + (size_t)(0 * B_ + b) * NOFF * HW_ + hw;
  const float* p1 = offp3 + (size_t)(1 * B_ + b) * NOFF * HW_ + hw;
  const float* p2 = offp3 + (size_t)(2 * B_ + b) * NOFF * HW_ + hw;

  float acc[12];
#pragma unroll
  for (int j = 0; j < 12; ++j) acc[j] = 0.f;

#pragma unroll
  for (int tap = 0; tap < 9; ++tap) {
    int ky = tap / 3 - 1;
    int kx = tap - (tap / 3) * 3 - 1;
    size_t ody = (size_t)(2 * tap) * HW_;
    size_t odx = (size_t)(2 * tap + 1) * HW_;
    float dyv = p0[ody] + p1[ody] + p2[ody];
    float dxv = p0[odx] + p1[odx] + p2[odx];
    dyv = fminf(fmaxf(dyv, -1.f), 1.f);
    dxv = fminf(fmaxf(dxv, -1.f), 1.f);
    float ys = (float)(h + ky) + dyv;
    float xs = (float)(w + kx) + dxv;
    float y0f = floorf(ys), x0f = floorf(xs);
    float ty = ys - y0f, tx = xs - x0f;
    int y0 = (int)y0f, x0 = (int)x0f;
    float fy0 = ((unsigned)y0 < (unsigned)H_) ? 1.f : 0.f;
    float fy1 = ((unsigned)(y0 + 1) < (unsigned)H_) ? 1.f : 0.f;
    float fx0 = ((unsigned)x0 < (unsigned)W_) ? 1.f : 0.f;
    float fx1 = ((unsigned)(x0 + 1) < (unsigned)W_) ? 1.f : 0.f;
    float omty = 1.f - ty, omtx = 1.f - tx;
    float w00 = omty * omtx * fy0 * fx0;
    float w01 = omty * tx * fy0 * fx1;
    float w10 = ty * omtx * fy1 * fx0;
    float w11 = ty * tx * fy1 * fx1;
    int ly0 = y0 - (h0 - 2);          // 0..7 (corner base)
    int lx0 = x0 - (w0 - 2);          // 0..7
    int posA = ly0 * 9 + lx0;
    int pA = posA * 384, sA = (posA & 7) << 4;
    int pB = pA + 384, sB = ((posA + 1) & 7) << 4;
    int pC = pA + 9 * 384, sC = ((posA + 9) & 7) << 4;
    int pD = pC + 384, sD = ((posA + 10) & 7) << 4;
#pragma unroll
    for (int rep = 0; rep < 3; ++rep) {
      int bo = lg * 8 + rep * 128;
      uint2 u00 = *(const uint2*)(sb + pA + (bo ^ sA));
      uint2 u01 = *(const uint2*)(sb + pB + (bo ^ sB));
      uint2 u10 = *(const uint2*)(sb + pC + (bo ^ sC));
      uint2 u11 = *(const uint2*)(sb + pD + (bo ^ sD));
      f32x4 dw = *(const f32x4*)&dcnT[tap * C_ + lg * 4 + rep * 64];
      float s0 = w00 * bflo(u00.x) + w01 * bflo(u01.x) + w10 * bflo(u10.x) + w11 * bflo(u11.x);
      float s1 = w00 * bfhi(u00.x) + w01 * bfhi(u01.x) + w10 * bfhi(u10.x) + w11 * bfhi(u11.x);
      float s2 = w00 * bflo(u00.y) + w01 * bflo(u01.y) + w10 * bflo(u10.y) + w11 * bflo(u11.y);
      float s3 = w00 * bfhi(u00.y) + w01 * bfhi(u01.y) + w10 * bfhi(u10.y) + w11 * bfhi(u11.y);
      acc[rep * 4 + 0] += s0 * dw.x;
      acc[rep * 4 + 1] += s1 * dw.y;
      acc[rep * 4 + 2] += s2 * dw.z;
      acc[rep * 4 + 3] += s3 * dw.w;
    }
  }

  size_t ob = ((size_t)b * HW_ + hw) * C_ + lg * 4;
#pragma unroll
  for (int rep = 0; rep < 3; ++rep) {
    uint2 pk;
    pk.x = (unsigned)f2bf(acc[rep * 4 + 0]) | ((unsigned)f2bf(acc[rep * 4 + 1]) << 16);
    pk.y = (unsigned)f2bf(acc[rep * 4 + 2]) | ((unsigned)f2bf(acc[rep * 4 + 3]) << 16);
    *(uint2*)(y1t + ob + rep * 64) = pk;
  }
}

// ---- K4: 64 px x 192 O per block (O split 2-way); pure-copy staging ------
__global__ __launch_bounds__(TPB) void k_gemm4(const unsigned short* __restrict__ y1t,
                                               const unsigned short* __restrict__ wtb,
                                               float* __restrict__ out) {
  __shared__ __align__(16) unsigned short bsm[64 * 192];  // 24 KB
  int tid = threadIdx.x;
  int n0 = blockIdx.x * 64;
  int mbase = blockIdx.y * 192;

  const uint4* src = (const uint4*)(y1t + (size_t)n0 * C_);  // 64*24 uint4
  char* sbase = (char*)bsm;
#pragma unroll
  for (int i = 0; i < 6; ++i) {
    int u = i * TPB + tid;            // 1536 units
    int row = u / 24;
    int c4 = u - row * 24;
    uint4 v = src[u];
    *(uint4*)(sbase + row * 384 + ((c4 * 16) ^ ((row & 7) << 4))) = v;
  }
  __syncthreads();

  int wid = tid >> 6;
  int lane = tid & 63;
  int col = lane & 15;
  int kg = lane >> 4;
  int wr = wid >> 1;                  // O-half (0,1)
  int wc = wid & 1;                   // px-half (0,1)

#pragma unroll 1
  for (int mi = 0; mi < 3; ++mi) {
    int m0 = mbase + mi * 64;
    f32x4 acc[2][2];
#pragma unroll
    for (int mf = 0; mf < 2; ++mf)
#pragma unroll
      for (int nf = 0; nf < 2; ++nf) acc[mf][nf] = (f32x4){0.f, 0.f, 0.f, 0.f};

#pragma unroll
    for (int k0 = 0; k0 < C_; k0 += 32) {
      short8v a[2], bfr[2];
#pragma unroll
      for (int mf = 0; mf < 2; ++mf)
        a[mf] = *(const short8v*)(wtb + (m0 + wr * 32 + mf * 16 + col) * C_ + k0 + kg * 8);
#pragma unroll
      for (int nf = 0; nf < 2; ++nf) {
        int brow = wc * 32 + nf * 16 + col;
        int kb = (k0 + kg * 8) * 2;
        bfr[nf] = *(const short8v*)(sbase + brow * 384 + (kb ^ ((brow & 7) << 4)));
      }
#pragma unroll
      for (int mf = 0; mf < 2; ++mf)
#pragma unroll
        for (int nf = 0; nf < 2; ++nf)
          acc[mf][nf] = __builtin_amdgcn_mfma_f32_16x16x32_bf16(a[mf], bfr[nf], acc[mf][nf], 0, 0, 0);
    }

#pragma unroll
    for (int mf = 0; mf < 2; ++mf) {
#pragma unroll
      for (int nf = 0; nf < 2; ++nf) {
        int p = n0 + wc * 32 + nf * 16 + col;
        int bb = p / HW_;
        int hw = p - bb * HW_;
#pragma unroll
        for (int reg = 0; reg < 4; ++reg) {
          int o = m0 + wr * 32 + mf * 16 + kg * 4 + reg;
          float a = acc[mf][nf][reg];
          float r = a * fminf(fmaxf(a + 3.f, 0.f), 6.f) * (1.f / 6.f);
          out[((size_t)bb * O_ + o) * HW_ + hw] = r;
        }
      }
    }
  }
}

extern "C" void kernel_launch(void* const* d_in, const int* in_sizes, int n_in,
                              void* d_out, int out_size, void* d_ws, size_t ws_size,
                              hipStream_t stream) {
  const float* x = (const float*)d_in[0];
  const float* og_dw = (const float*)d_in[1];
  const float* og_pw = (const float*)d_in[2];
  const float* dcn_w = (const float*)d_in[3];
  const float* pw_w = (const float*)d_in[4];
  float* out = (float*)d_out;

  float* ws = (float*)d_ws;
  float* offp3 = ws;                                     // 3*B*18*HW f32
  unsigned short* y1t = (unsigned short*)(offp3 + 3 * (size_t)B_ * NOFF * HW_);  // NPIX*C bf16
  unsigned short* wtb = y1t + (size_t)NPIX * C_;         // O*C bf16
  unsigned short* x_t = wtb + (size_t)O_ * C_;           // NPIX*C bf16
  unsigned short* w2b = x_t + (size_t)NPIX * C_;         // 32*1728 bf16

  k_prep<<<(O_ * C_ + 32 * K2 + TPB - 1) / TPB, TPB, 0, stream>>>(og_dw, og_pw, pw_w, wtb, w2b);
  k_xt<<<dim3(HW_ / 64, B_), TPB, 0, stream>>>(x, x_t);
  k_off2<<<dim3(W_ / 8, H_ / 8, B_ * 3), TPB, 0, stream>>>(x_t, w2b, offp3);
  k_deform9<<<dim3(196, B_), TPB, 0, stream>>>(x_t, offp3, dcn_w, y1t);
  k_gemm4<<<dim3(NPIX / 64, 2), TPB, 0, stream>>>(y1t, wtb, out);
}

// Round 13
// 93.923 us; speedup vs baseline: 1.4359x; 1.0474x over previous
//
#include <hip/hip_runtime.h>

#define TPB 256
constexpr int B_ = 8, C_ = 192, H_ = 56, W_ = 56, O_ = 384;
constexpr int HW_ = H_ * W_;          // 3136
constexpr int NOFF = 18;              // 9 taps * 2 (dy,dx)
constexpr int NPIX = B_ * HW_;        // 25088 = 196 * 128
constexpr int K2 = 9 * C_;            // 1728 combined-conv K

typedef __attribute__((ext_vector_type(8))) short short8v;
typedef __attribute__((ext_vector_type(4))) float f32x4;

__device__ inline unsigned short f2bf(float f) {
  unsigned u = __builtin_bit_cast(unsigned, f);
  unsigned r = (u + 0x7fffu + ((u >> 16) & 1u)) >> 16;
  return (unsigned short)r;
}
__device__ inline float bflo(unsigned u) {
  return __builtin_bit_cast(float, u << 16);
}
__device__ inline float bfhi(unsigned u) {
  return __builtin_bit_cast(float, u & 0xffff0000u);
}

// ---- K_PREP: wtb = bf16(pw_w); W2[o][tap*192+c] = og_pw[o,c]*og_dw[c,tap] -
__global__ __launch_bounds__(TPB) void k_prep(const float* __restrict__ og_dw,
                                              const float* __restrict__ og_pw,
                                              const float* __restrict__ pw,
                                              unsigned short* __restrict__ wtb,
                                              unsigned short* __restrict__ w2b) {
  int i = blockIdx.x * TPB + threadIdx.x;
  if (i < O_ * C_) wtb[i] = f2bf(pw[i]);
  int j = i - O_ * C_;
  if (j >= 0 && j < 32 * K2) {
    int o = j / K2, k = j - o * K2;
    int tap = k / C_, c = k - tap * C_;
    float v = 0.f;
    if (o < NOFF) v = og_pw[o * C_ + c] * og_dw[c * 9 + tap];
    w2b[j] = f2bf(v);
  }
}

// ---------------- K_XT: x[b][c][h][w] fp32 -> x_t[b][hw][c] bf16 ----------
__global__ __launch_bounds__(TPB) void k_xt(const float* __restrict__ x,
                                            unsigned short* __restrict__ xt) {
  __shared__ unsigned short tile[64 * 198];
  int tid = threadIdx.x;
  int P0 = blockIdx.x * 64;
  int b = blockIdx.y;
#pragma unroll
  for (int i = 0; i < 48; ++i) {
    int idx = i * TPB + tid;
    int px = idx & 63;
    int c = idx >> 6;
    float v = x[((size_t)(b * C_ + c)) * HW_ + P0 + px];
    tile[px * 198 + c] = f2bf(v);
  }
  __syncthreads();
  unsigned* xtu = (unsigned*)xt;
#pragma unroll
  for (int i = 0; i < 24; ++i) {
    int d = i * TPB + tid;            // dword index in 64*96
    int px = d / 96;
    int c2 = d - px * 96;
    unsigned v = *(const unsigned*)&tile[px * 198 + c2 * 2];
    xtu[((size_t)b * HW_ + P0 + px) * 96 + c2] = v;
  }
}

// ---- K_OFF2s: offset conv, K-split by tap-row; batch->XCD swizzled -------
// blockIdx.z: b = z & 7 (8 batches == 8 XCDs), s = z >> 3.
__global__ __launch_bounds__(TPB) void k_off2s(const unsigned short* __restrict__ xt,
                                               const unsigned short* __restrict__ w2b,
                                               float* __restrict__ offp3) {
  __shared__ __align__(16) unsigned short hal[80 * 192];  // 30.7 KB
  int tid = threadIdx.x;
  int w0 = blockIdx.x * 8;
  int h0 = blockIdx.y * 8;
  int bz = blockIdx.z;
  int b = bz & 7;                     // XCD-locality: batch b -> XCD b
  int s = bz >> 3;                    // tap-row split; dy = s-1
  int dy = s - 1;

  char* sb = (char*)hal;
  const uint4* xu4 = (const uint4*)xt;  // 16B = 8ch; 24 units per pixel
#pragma unroll
  for (int i = 0; i < 8; ++i) {
    int u = i * TPB + tid;            // 80 pos x 24 uint4 = 1920
    if (u < 1920) {
      int pos = u / 24, c4 = u - pos * 24;
      int ry = pos / 10;
      int gy = h0 + ry + dy;
      int gx = w0 - 1 + (pos - ry * 10);
      uint4 v = {0u, 0u, 0u, 0u};
      if ((unsigned)gy < (unsigned)H_ && (unsigned)gx < (unsigned)W_)
        v = xu4[((size_t)b * HW_ + gy * W_ + gx) * 24 + c4];
      *(uint4*)(sb + pos * 384 + ((c4 * 16) ^ ((pos & 7) << 4))) = v;
    }
  }
  __syncthreads();

  int wid = tid >> 6;
  int lane = tid & 63;
  int col = lane & 15;
  int kg = lane >> 4;
  int gpx = wid * 16 + col;           // tile-local pixel 0..63
  int py = gpx >> 3, px_ = gpx & 7;

  f32x4 acc0 = (f32x4){0.f, 0.f, 0.f, 0.f};
  f32x4 acc1 = (f32x4){0.f, 0.f, 0.f, 0.f};

#pragma unroll
  for (int j = 0; j < 3; ++j) {       // dx = j-1; tap = 3s+j
    int tap = 3 * s + j;
    int pos = py * 10 + px_ + j;
    int pbase = pos * 384;
    int psw = (pos & 7) << 4;
    const unsigned short* wrow = w2b + tap * C_ + kg * 8;
#pragma unroll
    for (int cs = 0; cs < 6; ++cs) {
      short8v bfrag = *(const short8v*)(sb + pbase + ((cs * 64 + kg * 16) ^ psw));
      short8v a0 = *(const short8v*)(wrow + cs * 32 + (size_t)col * K2);
      short8v a1 = *(const short8v*)(wrow + cs * 32 + (size_t)(16 + col) * K2);
      acc0 = __builtin_amdgcn_mfma_f32_16x16x32_bf16(a0, bfrag, acc0, 0, 0, 0);
      acc1 = __builtin_amdgcn_mfma_f32_16x16x32_bf16(a1, bfrag, acc1, 0, 0, 0);
    }
  }

  float* ob = offp3 + (size_t)(s * B_ + b) * NOFF * HW_ + (h0 + py) * W_ + w0 + px_;
#pragma unroll
  for (int reg = 0; reg < 4; ++reg) {
    int o0 = kg * 4 + reg;            // 0..15, always < 18
    ob[(size_t)o0 * HW_] = acc0[reg];
    int o1 = 16 + kg * 4 + reg;       // valid only for 16,17
    if (o1 < NOFF) ob[(size_t)o1 * HW_] = acc1[reg];
  }
}

// ---- K3: deform+dcn, LDS-halo, batch->XCD swizzled -----------------------
// 1-D grid 1568: b = bid & 7, tile = bid >> 3. Each XCD works one batch
// (x_t slice 1.2 MB -> resident in its private 4 MB L2).
__global__ __launch_bounds__(TPB) void k_deform9s(const unsigned short* __restrict__ xt,
                                                  const float* __restrict__ offp3,
                                                  const float* __restrict__ dcn,
                                                  unsigned short* __restrict__ y1t) {
  __shared__ __align__(16) unsigned short hal[81 * 192];  // 31.1 KB
  __shared__ __align__(16) float dcnT[9 * C_];            // 6.9 KB
  int tid = threadIdx.x;
  int bid = blockIdx.x;
  int b = bid & 7;                    // XCD-locality: batch b -> XCD b
  int tile = bid >> 3;
  int h0 = (tile / 14) * 4;
  int w0 = (tile - (tile / 14) * 14) * 4;

  for (int t = tid; t < 9 * C_; t += TPB) {
    int k = t / C_, c = t - k * C_;
    dcnT[t] = dcn[c * 9 + k];
  }
  char* sb = (char*)hal;
  const uint4* xu4 = (const uint4*)xt;
#pragma unroll
  for (int i = 0; i < 8; ++i) {
    int u = i * TPB + tid;            // 81 pos x 24 uint4 = 1944
    if (u < 1944) {
      int pos = u / 24, c4 = u - pos * 24;
      int ly = pos / 9, lx = pos - ly * 9;
      int gy = h0 - 2 + ly, gx = w0 - 2 + lx;
      uint4 v = {0u, 0u, 0u, 0u};
      if ((unsigned)gy < (unsigned)H_ && (unsigned)gx < (unsigned)W_)
        v = xu4[((size_t)b * HW_ + gy * W_ + gx) * 24 + c4];
      *(uint4*)(sb + pos * 384 + ((c4 * 16) ^ ((pos & 7) << 4))) = v;
    }
  }
  __syncthreads();

  int pl = tid >> 4;                  // 0..15: local pixel
  int lg = tid & 15;
  int py = pl >> 2, px_ = pl & 3;
  int h = h0 + py, w = w0 + px_;
  int hw = h * W_ + w;
  const float* p0 = offp3 + (size_t)(0 * B_ + b) * NOFF * HW_ + hw;
  const float* p1 = offp3 + (size_t)(1 * B_ + b) * NOFF * HW_ + hw;
  const float* p2 = offp3 + (size_t)(2 * B_ + b) * NOFF * HW_ + hw;

  float acc[12];
#pragma unroll
  for (int j = 0; j < 12; ++j) acc[j] = 0.f;

#pragma unroll
  for (int tap = 0; tap < 9; ++tap) {
    int ky = tap / 3 - 1;
    int kx = tap - (tap / 3) * 3 - 1;
    size_t ody = (size_t)(2 * tap) * HW_;
    size_t odx = (size_t)(2 * tap + 1) * HW_;
    float dyv = p0[ody] + p1[ody] + p2[ody];
    float dxv = p0[odx] + p1[odx] + p2[odx];
    dyv = fminf(fmaxf(dyv, -1.f), 1.f);
    dxv = fminf(fmaxf(dxv, -1.f), 1.f);
    float ys = (float)(h + ky) + dyv;
    float xs = (float)(w + kx) + dxv;
    float y0f = floorf(ys), x0f = floorf(xs);
    float ty = ys - y0f, tx = xs - x0f;
    int y0 = (int)y0f, x0 = (int)x0f;
    float fy0 = ((unsigned)y0 < (unsigned)H_) ? 1.f : 0.f;
    float fy1 = ((unsigned)(y0 + 1) < (unsigned)H_) ? 1.f : 0.f;
    float fx0 = ((unsigned)x0 < (unsigned)W_) ? 1.f : 0.f;
    float fx1 = ((unsigned)(x0 + 1) < (unsigned)W_) ? 1.f : 0.f;
    float omty = 1.f - ty, omtx = 1.f - tx;
    float w00 = omty * omtx * fy0 * fx0;
    float w01 = omty * tx * fy0 * fx1;
    float w10 = ty * omtx * fy1 * fx0;
    float w11 = ty * tx * fy1 * fx1;
    int ly0 = y0 - (h0 - 2);          // 0..7 (corner base)
    int lx0 = x0 - (w0 - 2);          // 0..7
    int posA = ly0 * 9 + lx0;
    int pA = posA * 384, sA = (posA & 7) << 4;
    int pB = pA + 384, sB = ((posA + 1) & 7) << 4;
    int pC = pA + 9 * 384, sC = ((posA + 9) & 7) << 4;
    int pD = pC + 384, sD = ((posA + 10) & 7) << 4;
#pragma unroll
    for (int rep = 0; rep < 3; ++rep) {
      int bo = lg * 8 + rep * 128;
      uint2 u00 = *(const uint2*)(sb + pA + (bo ^ sA));
      uint2 u01 = *(const uint2*)(sb + pB + (bo ^ sB));
      uint2 u10 = *(const uint2*)(sb + pC + (bo ^ sC));
      uint2 u11 = *(const uint2*)(sb + pD + (bo ^ sD));
      f32x4 dw = *(const f32x4*)&dcnT[tap * C_ + lg * 4 + rep * 64];
      float s0 = w00 * bflo(u00.x) + w01 * bflo(u01.x) + w10 * bflo(u10.x) + w11 * bflo(u11.x);
      float s1 = w00 * bfhi(u00.x) + w01 * bfhi(u01.x) + w10 * bfhi(u10.x) + w11 * bfhi(u11.x);
      float s2 = w00 * bflo(u00.y) + w01 * bflo(u01.y) + w10 * bflo(u10.y) + w11 * bflo(u11.y);
      float s3 = w00 * bfhi(u00.y) + w01 * bfhi(u01.y) + w10 * bfhi(u10.y) + w11 * bfhi(u11.y);
      acc[rep * 4 + 0] += s0 * dw.x;
      acc[rep * 4 + 1] += s1 * dw.y;
      acc[rep * 4 + 2] += s2 * dw.z;
      acc[rep * 4 + 3] += s3 * dw.w;
    }
  }

  size_t ob = ((size_t)b * HW_ + hw) * C_ + lg * 4;
#pragma unroll
  for (int rep = 0; rep < 3; ++rep) {
    uint2 pk;
    pk.x = (unsigned)f2bf(acc[rep * 4 + 0]) | ((unsigned)f2bf(acc[rep * 4 + 1]) << 16);
    pk.y = (unsigned)f2bf(acc[rep * 4 + 2]) | ((unsigned)f2bf(acc[rep * 4 + 3]) << 16);
    *(uint2*)(y1t + ob + rep * 64) = pk;
  }
}

// ---- K4: 64 px x 192 O per block (O split 2-way); pure-copy staging ------
__global__ __launch_bounds__(TPB) void k_gemm4(const unsigned short* __restrict__ y1t,
                                               const unsigned short* __restrict__ wtb,
                                               float* __restrict__ out) {
  __shared__ __align__(16) unsigned short bsm[64 * 192];  // 24 KB
  int tid = threadIdx.x;
  int n0 = blockIdx.x * 64;
  int mbase = blockIdx.y * 192;

  const uint4* src = (const uint4*)(y1t + (size_t)n0 * C_);  // 64*24 uint4
  char* sbase = (char*)bsm;
#pragma unroll
  for (int i = 0; i < 6; ++i) {
    int u = i * TPB + tid;            // 1536 units
    int row = u / 24;
    int c4 = u - row * 24;
    uint4 v = src[u];
    *(uint4*)(sbase + row * 384 + ((c4 * 16) ^ ((row & 7) << 4))) = v;
  }
  __syncthreads();

  int wid = tid >> 6;
  int lane = tid & 63;
  int col = lane & 15;
  int kg = lane >> 4;
  int wr = wid >> 1;                  // O-half (0,1)
  int wc = wid & 1;                   // px-half (0,1)

#pragma unroll 1
  for (int mi = 0; mi < 3; ++mi) {
    int m0 = mbase + mi * 64;
    f32x4 acc[2][2];
#pragma unroll
    for (int mf = 0; mf < 2; ++mf)
#pragma unroll
      for (int nf = 0; nf < 2; ++nf) acc[mf][nf] = (f32x4){0.f, 0.f, 0.f, 0.f};

#pragma unroll
    for (int k0 = 0; k0 < C_; k0 += 32) {
      short8v a[2], bfr[2];
#pragma unroll
      for (int mf = 0; mf < 2; ++mf)
        a[mf] = *(const short8v*)(wtb + (m0 + wr * 32 + mf * 16 + col) * C_ + k0 + kg * 8);
#pragma unroll
      for (int nf = 0; nf < 2; ++nf) {
        int brow = wc * 32 + nf * 16 + col;
        int kb = (k0 + kg * 8) * 2;
        bfr[nf] = *(const short8v*)(sbase + brow * 384 + (kb ^ ((brow & 7) << 4)));
      }
#pragma unroll
      for (int mf = 0; mf < 2; ++mf)
#pragma unroll
        for (int nf = 0; nf < 2; ++nf)
          acc[mf][nf] = __builtin_amdgcn_mfma_f32_16x16x32_bf16(a[mf], bfr[nf], acc[mf][nf], 0, 0, 0);
    }

#pragma unroll
    for (int mf = 0; mf < 2; ++mf) {
#pragma unroll
      for (int nf = 0; nf < 2; ++nf) {
        int p = n0 + wc * 32 + nf * 16 + col;
        int bb = p / HW_;
        int hw = p - bb * HW_;
#pragma unroll
        for (int reg = 0; reg < 4; ++reg) {
          int o = m0 + wr * 32 + mf * 16 + kg * 4 + reg;
          float a = acc[mf][nf][reg];
          float r = a * fminf(fmaxf(a + 3.f, 0.f), 6.f) * (1.f / 6.f);
          out[((size_t)bb * O_ + o) * HW_ + hw] = r;
        }
      }
    }
  }
}

extern "C" void kernel_launch(void* const* d_in, const int* in_sizes, int n_in,
                              void* d_out, int out_size, void* d_ws, size_t ws_size,
                              hipStream_t stream) {
  const float* x = (const float*)d_in[0];
  const float* og_dw = (const float*)d_in[1];
  const float* og_pw = (const float*)d_in[2];
  const float* dcn_w = (const float*)d_in[3];
  const float* pw_w = (const float*)d_in[4];
  float* out = (float*)d_out;

  float* ws = (float*)d_ws;
  float* offp3 = ws;                                     // 3*B*18*HW f32
  unsigned short* y1t = (unsigned short*)(offp3 + 3 * (size_t)B_ * NOFF * HW_);  // NPIX*C bf16
  unsigned short* wtb = y1t + (size_t)NPIX * C_;         // O*C bf16
  unsigned short* x_t = wtb + (size_t)O_ * C_;           // NPIX*C bf16
  unsigned short* w2b = x_t + (size_t)NPIX * C_;         // 32*1728 bf16

  k_prep<<<(O_ * C_ + 32 * K2 + TPB - 1) / TPB, TPB, 0, stream>>>(og_dw, og_pw, pw_w, wtb, w2b);
  k_xt<<<dim3(HW_ / 64, B_), TPB, 0, stream>>>(x, x_t);
  k_off2s<<<dim3(W_ / 8, H_ / 8, B_ * 3), TPB, 0, stream>>>(x_t, w2b, offp3);
  k_deform9s<<<196 * B_, TPB, 0, stream>>>(x_t, offp3, dcn_w, y1t);
  k_gemm4<<<dim3(NPIX / 64, 2), TPB, 0, stream>>>(y1t, wtb, out);
}

// Round 15
// 87.735 us; speedup vs baseline: 1.5372x; 1.0705x over previous
//
#include <hip/hip_runtime.h>
#include <hip/hip_fp16.h>

#define TPB 256
constexpr int B_ = 8, C_ = 192, H_ = 56, W_ = 56, O_ = 384;
constexpr int HW_ = H_ * W_;          // 3136
constexpr int NOFF = 18;              // 9 taps * 2 (dy,dx)
constexpr int NPIX = B_ * HW_;        // 25088 = 196 * 128
constexpr int K2 = 9 * C_;            // 1728 combined-conv K

typedef __attribute__((ext_vector_type(8))) short short8v;
typedef __attribute__((ext_vector_type(4))) float f32x4;

__device__ inline unsigned short f2bf(float f) {
  unsigned u = __builtin_bit_cast(unsigned, f);
  unsigned r = (u + 0x7fffu + ((u >> 16) & 1u)) >> 16;
  return (unsigned short)r;
}
__device__ inline float bflo(unsigned u) {
  return __builtin_bit_cast(float, u << 16);
}
__device__ inline float bfhi(unsigned u) {
  return __builtin_bit_cast(float, u & 0xffff0000u);
}
__device__ inline unsigned short f2h(float f) {
  return __half_as_ushort(__float2half(f));
}
__device__ inline float h2f(unsigned short u) {
  return __half2float(__ushort_as_half(u));
}

// ---- K_PREP: wtb=bf16(pw_w); W2 combined offset weights; dcnT_g[tap][c] ---
__global__ __launch_bounds__(TPB) void k_prep(const float* __restrict__ og_dw,
                                              const float* __restrict__ og_pw,
                                              const float* __restrict__ pw,
                                              const float* __restrict__ dcn,
                                              unsigned short* __restrict__ wtb,
                                              unsigned short* __restrict__ w2b,
                                              float* __restrict__ dcnT_g) {
  int i = blockIdx.x * TPB + threadIdx.x;
  if (i < O_ * C_) wtb[i] = f2bf(pw[i]);
  int j = i - O_ * C_;
  if (j >= 0 && j < 32 * K2) {
    int o = j / K2, k = j - o * K2;
    int tap = k / C_, c = k - tap * C_;
    float v = 0.f;
    if (o < NOFF) v = og_pw[o * C_ + c] * og_dw[c * 9 + tap];
    w2b[j] = f2bf(v);
  }
  int j2 = i - O_ * C_ - 32 * K2;
  if (j2 >= 0 && j2 < 9 * C_) {
    int k = j2 / C_, c = j2 - k * C_;
    dcnT_g[j2] = dcn[c * 9 + k];
  }
}

// ---------------- K_XT: x[b][c][h][w] fp32 -> x_t[b][hw][c] bf16 ----------
__global__ __launch_bounds__(TPB) void k_xt(const float* __restrict__ x,
                                            unsigned short* __restrict__ xt) {
  __shared__ unsigned short tile[64 * 198];
  int tid = threadIdx.x;
  int P0 = blockIdx.x * 64;
  int b = blockIdx.y;
#pragma unroll
  for (int i = 0; i < 48; ++i) {
    int idx = i * TPB + tid;
    int px = idx & 63;
    int c = idx >> 6;
    float v = x[((size_t)(b * C_ + c)) * HW_ + P0 + px];
    tile[px * 198 + c] = f2bf(v);
  }
  __syncthreads();
  unsigned* xtu = (unsigned*)xt;
#pragma unroll
  for (int i = 0; i < 24; ++i) {
    int d = i * TPB + tid;            // dword index in 64*96
    int px = d / 96;
    int c2 = d - px * 96;
    unsigned v = *(const unsigned*)&tile[px * 198 + c2 * 2];
    xtu[((size_t)b * HW_ + P0 + px) * 96 + c2] = v;
  }
}

// ---- K_OFF2s: offset conv, K-split by tap-row; batch->XCD swizzled -------
__global__ __launch_bounds__(TPB) void k_off2s(const unsigned short* __restrict__ xt,
                                               const unsigned short* __restrict__ w2b,
                                               float* __restrict__ offp3) {
  __shared__ __align__(16) unsigned short hal[80 * 192];  // 30.7 KB
  int tid = threadIdx.x;
  int w0 = blockIdx.x * 8;
  int h0 = blockIdx.y * 8;
  int bz = blockIdx.z;
  int b = bz & 7;                     // XCD-locality: batch b -> XCD b
  int s = bz >> 3;                    // tap-row split; dy = s-1
  int dy = s - 1;

  char* sb = (char*)hal;
  const uint4* xu4 = (const uint4*)xt;  // 16B = 8ch; 24 units per pixel
#pragma unroll
  for (int i = 0; i < 8; ++i) {
    int u = i * TPB + tid;            // 80 pos x 24 uint4 = 1920
    if (u < 1920) {
      int pos = u / 24, c4 = u - pos * 24;
      int ry = pos / 10;
      int gy = h0 + ry + dy;
      int gx = w0 - 1 + (pos - ry * 10);
      uint4 v = {0u, 0u, 0u, 0u};
      if ((unsigned)gy < (unsigned)H_ && (unsigned)gx < (unsigned)W_)
        v = xu4[((size_t)b * HW_ + gy * W_ + gx) * 24 + c4];
      *(uint4*)(sb + pos * 384 + ((c4 * 16) ^ ((pos & 7) << 4))) = v;
    }
  }
  __syncthreads();

  int wid = tid >> 6;
  int lane = tid & 63;
  int col = lane & 15;
  int kg = lane >> 4;
  int gpx = wid * 16 + col;           // tile-local pixel 0..63
  int py = gpx >> 3, px_ = gpx & 7;

  f32x4 acc0 = (f32x4){0.f, 0.f, 0.f, 0.f};
  f32x4 acc1 = (f32x4){0.f, 0.f, 0.f, 0.f};

#pragma unroll
  for (int j = 0; j < 3; ++j) {       // dx = j-1; tap = 3s+j
    int tap = 3 * s + j;
    int pos = py * 10 + px_ + j;
    int pbase = pos * 384;
    int psw = (pos & 7) << 4;
    const unsigned short* wrow = w2b + tap * C_ + kg * 8;
#pragma unroll
    for (int cs = 0; cs < 6; ++cs) {
      short8v bfrag = *(const short8v*)(sb + pbase + ((cs * 64 + kg * 16) ^ psw));
      short8v a0 = *(const short8v*)(wrow + cs * 32 + (size_t)col * K2);
      short8v a1 = *(const short8v*)(wrow + cs * 32 + (size_t)(16 + col) * K2);
      acc0 = __builtin_amdgcn_mfma_f32_16x16x32_bf16(a0, bfrag, acc0, 0, 0, 0);
      acc1 = __builtin_amdgcn_mfma_f32_16x16x32_bf16(a1, bfrag, acc1, 0, 0, 0);
    }
  }

  float* ob = offp3 + (size_t)(s * B_ + b) * NOFF * HW_ + (h0 + py) * W_ + w0 + px_;
#pragma unroll
  for (int reg = 0; reg < 4; ++reg) {
    int o0 = kg * 4 + reg;            // 0..15, always < 18
    ob[(size_t)o0 * HW_] = acc0[reg];
    int o1 = 16 + kg * 4 + reg;       // valid only for 16,17
    if (o1 < NOFF) ob[(size_t)o1 * HW_] = acc1[reg];
  }
}

// ---- K3: deform+dcn; 8x4 px tile, 512 thr, phase-split weight compute ----
// Phase 1: 288 threads compute (px,tap) weights once -> LDS wtab.
// Phase 2: 16 lanes/px blend from swizzled LDS halo (117 pos).
__global__ __launch_bounds__(512, 8) void k_deform10(const unsigned short* __restrict__ xt,
                                                     const float* __restrict__ offp3,
                                                     const float* __restrict__ dcnT_g,
                                                     unsigned short* __restrict__ y1t) {
  __shared__ __align__(16) unsigned short hal[117 * 192];  // 44.9 KB
  __shared__ __align__(16) unsigned wtab[32 * 9 * 4];      // 4.6 KB
  int tid = threadIdx.x;
  int bid = blockIdx.x;
  int b = bid & 7;                    // XCD-locality: batch b -> XCD b
  int tile = bid >> 3;                // 0..97
  int ty = tile / 7;
  int h0 = ty * 4;
  int w0 = (tile - ty * 7) * 8;

  char* sb = (char*)hal;
  const uint4* xu4 = (const uint4*)xt;
#pragma unroll
  for (int i = 0; i < 6; ++i) {
    int u = i * 512 + tid;            // 117 pos x 24 uint4 = 2808
    if (u < 2808) {
      int pos = u / 24, c4 = u - pos * 24;
      int ly = pos / 13, lx = pos - ly * 13;
      int gy = h0 - 2 + ly, gx = w0 - 2 + lx;
      uint4 v = {0u, 0u, 0u, 0u};
      if ((unsigned)gy < (unsigned)H_ && (unsigned)gx < (unsigned)W_)
        v = xu4[((size_t)b * HW_ + gy * W_ + gx) * 24 + c4];
      *(uint4*)(sb + pos * 384 + ((c4 * 16) ^ ((pos & 7) << 4))) = v;
    }
  }

  if (tid < 288) {                    // 32 px x 9 taps
    int pxl = tid / 9, tap = tid - pxl * 9;
    int py = pxl >> 3, pxx = pxl & 7;
    int h = h0 + py, w = w0 + pxx;
    int hw = h * W_ + w;
    const float* p0 = offp3 + (size_t)b * NOFF * HW_ + hw;
    const float* p1 = p0 + (size_t)B_ * NOFF * HW_;
    const float* p2 = p1 + (size_t)B_ * NOFF * HW_;
    int t3 = tap / 3;
    int ky = t3 - 1, kx = tap - t3 * 3 - 1;
    size_t ody = (size_t)(2 * tap) * HW_;
    size_t odx = ody + HW_;
    float dyv = p0[ody] + p1[ody] + p2[ody];
    float dxv = p0[odx] + p1[odx] + p2[odx];
    dyv = fminf(fmaxf(dyv, -1.f), 1.f);
    dxv = fminf(fmaxf(dxv, -1.f), 1.f);
    float ys = (float)(h + ky) + dyv;
    float xs = (float)(w + kx) + dxv;
    float y0f = floorf(ys), x0f = floorf(xs);
    float tyf = ys - y0f, txf = xs - x0f;
    int y0 = (int)y0f, x0 = (int)x0f;
    float fy0 = ((unsigned)y0 < (unsigned)H_) ? 1.f : 0.f;
    float fy1 = ((unsigned)(y0 + 1) < (unsigned)H_) ? 1.f : 0.f;
    float fx0 = ((unsigned)x0 < (unsigned)W_) ? 1.f : 0.f;
    float fx1 = ((unsigned)(x0 + 1) < (unsigned)W_) ? 1.f : 0.f;
    float omty = 1.f - tyf, omtx = 1.f - txf;
    float w00 = omty * omtx * fy0 * fx0;
    float w01 = omty * txf * fy0 * fx1;
    float w10 = tyf * omtx * fy1 * fx0;
    float w11 = tyf * txf * fy1 * fx1;
    int posA = (y0 - (h0 - 2)) * 13 + (x0 - (w0 - 2));
    uint4 e;
    e.x = (unsigned)f2h(w00) | ((unsigned)f2h(w01) << 16);
    e.y = (unsigned)f2h(w10) | ((unsigned)f2h(w11) << 16);
    e.z = (unsigned)posA;
    e.w = 0u;
    *(uint4*)&wtab[(size_t)tid * 4] = e;
  }
  __syncthreads();

  int pl = tid >> 4;                  // 0..31: local pixel
  int lg = tid & 15;
  int py = pl >> 3, pxx = pl & 7;
  int hw = (h0 + py) * W_ + w0 + pxx;

  float acc[12];
#pragma unroll
  for (int j = 0; j < 12; ++j) acc[j] = 0.f;

#pragma unroll
  for (int tap = 0; tap < 9; ++tap) {
    uint4 e = *(const uint4*)&wtab[(size_t)(pl * 9 + tap) * 4];
    float w00 = h2f((unsigned short)(e.x & 0xffffu));
    float w01 = h2f((unsigned short)(e.x >> 16));
    float w10 = h2f((unsigned short)(e.y & 0xffffu));
    float w11 = h2f((unsigned short)(e.y >> 16));
    int posA = (int)e.z;
    int pA = posA * 384, sA = (posA & 7) << 4;
    int pB = pA + 384, sB = ((posA + 1) & 7) << 4;
    int pC = pA + 13 * 384, sC = ((posA + 13) & 7) << 4;
    int pD = pC + 384, sD = ((posA + 14) & 7) << 4;
#pragma unroll
    for (int rep = 0; rep < 3; ++rep) {
      int bo = lg * 8 + rep * 128;
      uint2 u00 = *(const uint2*)(sb + pA + (bo ^ sA));
      uint2 u01 = *(const uint2*)(sb + pB + (bo ^ sB));
      uint2 u10 = *(const uint2*)(sb + pC + (bo ^ sC));
      uint2 u11 = *(const uint2*)(sb + pD + (bo ^ sD));
      f32x4 dw = *(const f32x4*)&dcnT_g[tap * C_ + lg * 4 + rep * 64];
      float s0 = w00 * bflo(u00.x) + w01 * bflo(u01.x) + w10 * bflo(u10.x) + w11 * bflo(u11.x);
      float s1 = w00 * bfhi(u00.x) + w01 * bfhi(u01.x) + w10 * bfhi(u10.x) + w11 * bfhi(u11.x);
      float s2 = w00 * bflo(u00.y) + w01 * bflo(u01.y) + w10 * bflo(u10.y) + w11 * bflo(u11.y);
      float s3 = w00 * bfhi(u00.y) + w01 * bfhi(u01.y) + w10 * bfhi(u10.y) + w11 * bfhi(u11.y);
      acc[rep * 4 + 0] += s0 * dw.x;
      acc[rep * 4 + 1] += s1 * dw.y;
      acc[rep * 4 + 2] += s2 * dw.z;
      acc[rep * 4 + 3] += s3 * dw.w;
    }
  }

  size_t ob = ((size_t)b * HW_ + hw) * C_ + lg * 4;
#pragma unroll
  for (int rep = 0; rep < 3; ++rep) {
    uint2 pk;
    pk.x = (unsigned)f2bf(acc[rep * 4 + 0]) | ((unsigned)f2bf(acc[rep * 4 + 1]) << 16);
    pk.y = (unsigned)f2bf(acc[rep * 4 + 2]) | ((unsigned)f2bf(acc[rep * 4 + 3]) << 16);
    *(uint2*)(y1t + ob + rep * 64) = pk;
  }
}

// ---- K4: 64 px x 192 O per block (O split 2-way); pure-copy staging ------
__global__ __launch_bounds__(TPB) void k_gemm4(const unsigned short* __restrict__ y1t,
                                               const unsigned short* __restrict__ wtb,
                                               float* __restrict__ out) {
  __shared__ __align__(16) unsigned short bsm[64 * 192];  // 24 KB
  int tid = threadIdx.x;
  int n0 = blockIdx.x * 64;
  int mbase = blockIdx.y * 192;

  const uint4* src = (const uint4*)(y1t + (size_t)n0 * C_);  // 64*24 uint4
  char* sbase = (char*)bsm;
#pragma unroll
  for (int i = 0; i < 6; ++i) {
    int u = i * TPB + tid;            // 1536 units
    int row = u / 24;
    int c4 = u - row * 24;
    uint4 v = src[u];
    *(uint4*)(sbase + row * 384 + ((c4 * 16) ^ ((row & 7) << 4))) = v;
  }
  __syncthreads();

  int wid = tid >> 6;
  int lane = tid & 63;
  int col = lane & 15;
  int kg = lane >> 4;
  int wr = wid >> 1;                  // O-half (0,1)
  int wc = wid & 1;                   // px-half (0,1)

#pragma unroll 1
  for (int mi = 0; mi < 3; ++mi) {
    int m0 = mbase + mi * 64;
    f32x4 acc[2][2];
#pragma unroll
    for (int mf = 0; mf < 2; ++mf)
#pragma unroll
      for (int nf = 0; nf < 2; ++nf) acc[mf][nf] = (f32x4){0.f, 0.f, 0.f, 0.f};

#pragma unroll
    for (int k0 = 0; k0 < C_; k0 += 32) {
      short8v a[2], bfr[2];
#pragma unroll
      for (int mf = 0; mf < 2; ++mf)
        a[mf] = *(const short8v*)(wtb + (m0 + wr * 32 + mf * 16 + col) * C_ + k0 + kg * 8);
#pragma unroll
      for (int nf = 0; nf < 2; ++nf) {
        int brow = wc * 32 + nf * 16 + col;
        int kb = (k0 + kg * 8) * 2;
        bfr[nf] = *(const short8v*)(sbase + brow * 384 + (kb ^ ((brow & 7) << 4)));
      }
#pragma unroll
      for (int mf = 0; mf < 2; ++mf)
#pragma unroll
        for (int nf = 0; nf < 2; ++nf)
          acc[mf][nf] = __builtin_amdgcn_mfma_f32_16x16x32_bf16(a[mf], bfr[nf], acc[mf][nf], 0, 0, 0);
    }

#pragma unroll
    for (int mf = 0; mf < 2; ++mf) {
#pragma unroll
      for (int nf = 0; nf < 2; ++nf) {
        int p = n0 + wc * 32 + nf * 16 + col;
        int bb = p / HW_;
        int hw = p - bb * HW_;
#pragma unroll
        for (int reg = 0; reg < 4; ++reg) {
          int o = m0 + wr * 32 + mf * 16 + kg * 4 + reg;
          float a = acc[mf][nf][reg];
          float r = a * fminf(fmaxf(a + 3.f, 0.f), 6.f) * (1.f / 6.f);
          out[((size_t)bb * O_ + o) * HW_ + hw] = r;
        }
      }
    }
  }
}

extern "C" void kernel_launch(void* const* d_in, const int* in_sizes, int n_in,
                              void* d_out, int out_size, void* d_ws, size_t ws_size,
                              hipStream_t stream) {
  const float* x = (const float*)d_in[0];
  const float* og_dw = (const float*)d_in[1];
  const float* og_pw = (const float*)d_in[2];
  const float* dcn_w = (const float*)d_in[3];
  const float* pw_w = (const float*)d_in[4];
  float* out = (float*)d_out;

  float* ws = (float*)d_ws;
  float* offp3 = ws;                                     // 3*B*18*HW f32
  float* dcnT_g = offp3 + 3 * (size_t)B_ * NOFF * HW_;   // 9*C f32
  unsigned short* y1t = (unsigned short*)(dcnT_g + 9 * C_);  // NPIX*C bf16
  unsigned short* wtb = y1t + (size_t)NPIX * C_;         // O*C bf16
  unsigned short* x_t = wtb + (size_t)O_ * C_;           // NPIX*C bf16
  unsigned short* w2b = x_t + (size_t)NPIX * C_;         // 32*1728 bf16

  k_prep<<<(O_ * C_ + 32 * K2 + 9 * C_ + TPB - 1) / TPB, TPB, 0, stream>>>(
      og_dw, og_pw, pw_w, dcn_w, wtb, w2b, dcnT_g);
  k_xt<<<dim3(HW_ / 64, B_), TPB, 0, stream>>>(x, x_t);
  k_off2s<<<dim3(W_ / 8, H_ / 8, B_ * 3), TPB, 0, stream>>>(x_t, w2b, offp3);
  k_deform10<<<196 * 4 * B_ / 8, 512, 0, stream>>>(x_t, offp3, dcnT_g, y1t);
  k_gemm4<<<dim3(NPIX / 64, 2), TPB, 0, stream>>>(y1t, wtb, out);
}

// Round 16
// 83.702 us; speedup vs baseline: 1.6113x; 1.0482x over previous
//
#include <hip/hip_runtime.h>
#include <hip/hip_fp16.h>

#define TPB 256
constexpr int B_ = 8, C_ = 192, H_ = 56, W_ = 56, O_ = 384;
constexpr int HW_ = H_ * W_;          // 3136
constexpr int NOFF = 18;              // 9 taps * 2 (dy,dx)
constexpr int NPIX = B_ * HW_;        // 25088 = 196 * 128
constexpr int K2 = 9 * C_;            // 1728 combined-conv K

typedef __attribute__((ext_vector_type(8))) short short8v;
typedef __attribute__((ext_vector_type(4))) float f32x4;
typedef __attribute__((ext_vector_type(2))) float f32x2;

__device__ inline unsigned short f2bf(float f) {
  unsigned u = __builtin_bit_cast(unsigned, f);
  unsigned r = (u + 0x7fffu + ((u >> 16) & 1u)) >> 16;
  return (unsigned short)r;
}
__device__ inline float bflo(unsigned u) {
  return __builtin_bit_cast(float, u << 16);
}
__device__ inline float bfhi(unsigned u) {
  return __builtin_bit_cast(float, u & 0xffff0000u);
}

// ---- K_PREP: wtb=bf16(pw_w); W2 combined offset weights; dcnT_g[tap][c] ---
__global__ __launch_bounds__(TPB) void k_prep(const float* __restrict__ og_dw,
                                              const float* __restrict__ og_pw,
                                              const float* __restrict__ pw,
                                              const float* __restrict__ dcn,
                                              unsigned short* __restrict__ wtb,
                                              unsigned short* __restrict__ w2b,
                                              float* __restrict__ dcnT_g) {
  int i = blockIdx.x * TPB + threadIdx.x;
  if (i < O_ * C_) wtb[i] = f2bf(pw[i]);
  int j = i - O_ * C_;
  if (j >= 0 && j < 32 * K2) {
    int o = j / K2, k = j - o * K2;
    int tap = k / C_, c = k - tap * C_;
    float v = 0.f;
    if (o < NOFF) v = og_pw[o * C_ + c] * og_dw[c * 9 + tap];
    w2b[j] = f2bf(v);
  }
  int j2 = i - O_ * C_ - 32 * K2;
  if (j2 >= 0 && j2 < 9 * C_) {
    int k = j2 / C_, c = j2 - k * C_;
    dcnT_g[j2] = dcn[c * 9 + k];
  }
}

// ---------------- K_XT: x[b][c][h][w] fp32 -> x_t[b][hw][c] bf16 ----------
__global__ __launch_bounds__(TPB) void k_xt(const float* __restrict__ x,
                                            unsigned short* __restrict__ xt) {
  __shared__ unsigned short tile[64 * 198];
  int tid = threadIdx.x;
  int P0 = blockIdx.x * 64;
  int b = blockIdx.y;
#pragma unroll
  for (int i = 0; i < 48; ++i) {
    int idx = i * TPB + tid;
    int px = idx & 63;
    int c = idx >> 6;
    float v = x[((size_t)(b * C_ + c)) * HW_ + P0 + px];
    tile[px * 198 + c] = f2bf(v);
  }
  __syncthreads();
  unsigned* xtu = (unsigned*)xt;
#pragma unroll
  for (int i = 0; i < 24; ++i) {
    int d = i * TPB + tid;            // dword index in 64*96
    int px = d / 96;
    int c2 = d - px * 96;
    unsigned v = *(const unsigned*)&tile[px * 198 + c2 * 2];
    xtu[((size_t)b * HW_ + P0 + px) * 96 + c2] = v;
  }
}

// ---- K_OFF2s: offset conv, K-split by tap-row; batch->XCD swizzled -------
__global__ __launch_bounds__(TPB) void k_off2s(const unsigned short* __restrict__ xt,
                                               const unsigned short* __restrict__ w2b,
                                               float* __restrict__ offp3) {
  __shared__ __align__(16) unsigned short hal[80 * 192];  // 30.7 KB
  int tid = threadIdx.x;
  int w0 = blockIdx.x * 8;
  int h0 = blockIdx.y * 8;
  int bz = blockIdx.z;
  int b = bz & 7;                     // XCD-locality: batch b -> XCD b
  int s = bz >> 3;                    // tap-row split; dy = s-1
  int dy = s - 1;

  char* sb = (char*)hal;
  const uint4* xu4 = (const uint4*)xt;  // 16B = 8ch; 24 units per pixel
#pragma unroll
  for (int i = 0; i < 8; ++i) {
    int u = i * TPB + tid;            // 80 pos x 24 uint4 = 1920
    if (u < 1920) {
      int pos = u / 24, c4 = u - pos * 24;
      int ry = pos / 10;
      int gy = h0 + ry + dy;
      int gx = w0 - 1 + (pos - ry * 10);
      uint4 v = {0u, 0u, 0u, 0u};
      if ((unsigned)gy < (unsigned)H_ && (unsigned)gx < (unsigned)W_)
        v = xu4[((size_t)b * HW_ + gy * W_ + gx) * 24 + c4];
      *(uint4*)(sb + pos * 384 + ((c4 * 16) ^ ((pos & 7) << 4))) = v;
    }
  }
  __syncthreads();

  int wid = tid >> 6;
  int lane = tid & 63;
  int col = lane & 15;
  int kg = lane >> 4;
  int gpx = wid * 16 + col;           // tile-local pixel 0..63
  int py = gpx >> 3, px_ = gpx & 7;

  f32x4 acc0 = (f32x4){0.f, 0.f, 0.f, 0.f};
  f32x4 acc1 = (f32x4){0.f, 0.f, 0.f, 0.f};

#pragma unroll
  for (int j = 0; j < 3; ++j) {       // dx = j-1; tap = 3s+j
    int tap = 3 * s + j;
    int pos = py * 10 + px_ + j;
    int pbase = pos * 384;
    int psw = (pos & 7) << 4;
    const unsigned short* wrow = w2b + tap * C_ + kg * 8;
#pragma unroll
    for (int cs = 0; cs < 6; ++cs) {
      short8v bfrag = *(const short8v*)(sb + pbase + ((cs * 64 + kg * 16) ^ psw));
      short8v a0 = *(const short8v*)(wrow + cs * 32 + (size_t)col * K2);
      short8v a1 = *(const short8v*)(wrow + cs * 32 + (size_t)(16 + col) * K2);
      acc0 = __builtin_amdgcn_mfma_f32_16x16x32_bf16(a0, bfrag, acc0, 0, 0, 0);
      acc1 = __builtin_amdgcn_mfma_f32_16x16x32_bf16(a1, bfrag, acc1, 0, 0, 0);
    }
  }

  float* ob = offp3 + (size_t)(s * B_ + b) * NOFF * HW_ + (h0 + py) * W_ + w0 + px_;
#pragma unroll
  for (int reg = 0; reg < 4; ++reg) {
    int o0 = kg * 4 + reg;            // 0..15, always < 18
    ob[(size_t)o0 * HW_] = acc0[reg];
    int o1 = 16 + kg * 4 + reg;       // valid only for 16,17
    if (o1 < NOFF) ob[(size_t)o1 * HW_] = acc1[reg];
  }
}

// ---- K3: deform+dcn; 8x4 tile, 512 thr, LINEAR halo, f32 wtab, pk-f32 ----
// Deform reads are row-contiguous (16 lanes x 8B) -> no bank conflict ->
// swizzle removed (saves ~300 VALU/thread). Blend in float2 (v_pk_fma_f32).
__global__ __launch_bounds__(512, 8) void k_deform11(const unsigned short* __restrict__ xt,
                                                     const float* __restrict__ offp3,
                                                     const float* __restrict__ dcnT_g,
                                                     unsigned short* __restrict__ y1t) {
  __shared__ __align__(16) unsigned short hal[117 * 192];  // 44.9 KB linear
  __shared__ __align__(16) f32x4 w4tab[288];               // 4.6 KB
  __shared__ int postab[288];                              // 1.2 KB
  int tid = threadIdx.x;
  int bid = blockIdx.x;
  int b = bid & 7;                    // XCD-locality: batch b -> XCD b
  int tile = bid >> 3;                // 0..97
  int ty = tile / 7;
  int h0 = ty * 4;
  int w0 = (tile - ty * 7) * 8;

  uint4* halu4 = (uint4*)hal;
  const uint4* xu4 = (const uint4*)xt;
#pragma unroll
  for (int i = 0; i < 6; ++i) {
    int u = i * 512 + tid;            // 117 pos x 24 uint4 = 2808
    if (u < 2808) {
      int pos = u / 24;
      int ly = pos / 13, lx = pos - ly * 13;
      int gy = h0 - 2 + ly, gx = w0 - 2 + lx;
      uint4 v = {0u, 0u, 0u, 0u};
      if ((unsigned)gy < (unsigned)H_ && (unsigned)gx < (unsigned)W_)
        v = xu4[((size_t)b * HW_ + gy * W_ + gx) * 24 + (u - pos * 24)];
      halu4[u] = v;                   // linear: pos*24 + c4 == u
    }
  }

  if (tid < 288) {                    // 32 px x 9 taps
    int pxl = tid / 9, tap = tid - pxl * 9;
    int py = pxl >> 3, pxx = pxl & 7;
    int h = h0 + py, w = w0 + pxx;
    int hw = h * W_ + w;
    const float* p0 = offp3 + (size_t)b * NOFF * HW_ + hw;
    const float* p1 = p0 + (size_t)B_ * NOFF * HW_;
    const float* p2 = p1 + (size_t)B_ * NOFF * HW_;
    int t3 = tap / 3;
    int ky = t3 - 1, kx = tap - t3 * 3 - 1;
    size_t ody = (size_t)(2 * tap) * HW_;
    size_t odx = ody + HW_;
    float dyv = p0[ody] + p1[ody] + p2[ody];
    float dxv = p0[odx] + p1[odx] + p2[odx];
    dyv = fminf(fmaxf(dyv, -1.f), 1.f);
    dxv = fminf(fmaxf(dxv, -1.f), 1.f);
    float ys = (float)(h + ky) + dyv;
    float xs = (float)(w + kx) + dxv;
    float y0f = floorf(ys), x0f = floorf(xs);
    float tyf = ys - y0f, txf = xs - x0f;
    int y0 = (int)y0f, x0 = (int)x0f;
    float fy0 = ((unsigned)y0 < (unsigned)H_) ? 1.f : 0.f;
    float fy1 = ((unsigned)(y0 + 1) < (unsigned)H_) ? 1.f : 0.f;
    float fx0 = ((unsigned)x0 < (unsigned)W_) ? 1.f : 0.f;
    float fx1 = ((unsigned)(x0 + 1) < (unsigned)W_) ? 1.f : 0.f;
    float omty = 1.f - tyf, omtx = 1.f - txf;
    f32x4 w4;
    w4.x = omty * omtx * fy0 * fx0;
    w4.y = omty * txf * fy0 * fx1;
    w4.z = tyf * omtx * fy1 * fx0;
    w4.w = tyf * txf * fy1 * fx1;
    w4tab[tid] = w4;
    postab[tid] = (y0 - (h0 - 2)) * 13 + (x0 - (w0 - 2));
  }
  __syncthreads();

  int pl = tid >> 4;                  // 0..31: local pixel
  int lg = tid & 15;
  int py = pl >> 3, pxx = pl & 7;
  int hw = (h0 + py) * W_ + w0 + pxx;
  int co0 = lg * 4;

  f32x2 acc2[6];
#pragma unroll
  for (int j = 0; j < 6; ++j) acc2[j] = (f32x2){0.f, 0.f};

#pragma unroll
  for (int tap = 0; tap < 9; ++tap) {
    f32x4 w4 = w4tab[pl * 9 + tap];
    int posA = postab[pl * 9 + tap];
    const unsigned short* base = hal + posA * 192 + co0;
#pragma unroll
    for (int rep = 0; rep < 3; ++rep) {
      int co = rep * 64;
      uint2 u00 = *(const uint2*)(base + co);
      uint2 u01 = *(const uint2*)(base + 192 + co);
      uint2 u10 = *(const uint2*)(base + 13 * 192 + co);
      uint2 u11 = *(const uint2*)(base + 14 * 192 + co);
      f32x4 dw = *(const f32x4*)&dcnT_g[tap * C_ + co0 + co];
      f32x2 v00l = (f32x2){bflo(u00.x), bfhi(u00.x)};
      f32x2 v01l = (f32x2){bflo(u01.x), bfhi(u01.x)};
      f32x2 v10l = (f32x2){bflo(u10.x), bfhi(u10.x)};
      f32x2 v11l = (f32x2){bflo(u11.x), bfhi(u11.x)};
      f32x2 v00h = (f32x2){bflo(u00.y), bfhi(u00.y)};
      f32x2 v01h = (f32x2){bflo(u01.y), bfhi(u01.y)};
      f32x2 v10h = (f32x2){bflo(u10.y), bfhi(u10.y)};
      f32x2 v11h = (f32x2){bflo(u11.y), bfhi(u11.y)};
      f32x2 sl = v00l * w4.x + v01l * w4.y + v10l * w4.z + v11l * w4.w;
      f32x2 sh = v00h * w4.x + v01h * w4.y + v10h * w4.z + v11h * w4.w;
      acc2[rep * 2 + 0] += sl * (f32x2){dw.x, dw.y};
      acc2[rep * 2 + 1] += sh * (f32x2){dw.z, dw.w};
    }
  }

  size_t ob = ((size_t)b * HW_ + hw) * C_ + co0;
#pragma unroll
  for (int rep = 0; rep < 3; ++rep) {
    uint2 pk;
    pk.x = (unsigned)f2bf(acc2[rep * 2][0]) | ((unsigned)f2bf(acc2[rep * 2][1]) << 16);
    pk.y = (unsigned)f2bf(acc2[rep * 2 + 1][0]) | ((unsigned)f2bf(acc2[rep * 2 + 1][1]) << 16);
    *(uint2*)(y1t + ob + rep * 64) = pk;
  }
}

// ---- K4: 64 px x 192 O per block (O split 2-way); pure-copy staging ------
__global__ __launch_bounds__(TPB) void k_gemm4(const unsigned short* __restrict__ y1t,
                                               const unsigned short* __restrict__ wtb,
                                               float* __restrict__ out) {
  __shared__ __align__(16) unsigned short bsm[64 * 192];  // 24 KB
  int tid = threadIdx.x;
  int n0 = blockIdx.x * 64;
  int mbase = blockIdx.y * 192;

  const uint4* src = (const uint4*)(y1t + (size_t)n0 * C_);  // 64*24 uint4
  char* sbase = (char*)bsm;
#pragma unroll
  for (int i = 0; i < 6; ++i) {
    int u = i * TPB + tid;            // 1536 units
    int row = u / 24;
    int c4 = u - row * 24;
    uint4 v = src[u];
    *(uint4*)(sbase + row * 384 + ((c4 * 16) ^ ((row & 7) << 4))) = v;
  }
  __syncthreads();

  int wid = tid >> 6;
  int lane = tid & 63;
  int col = lane & 15;
  int kg = lane >> 4;
  int wr = wid >> 1;                  // O-half (0,1)
  int wc = wid & 1;                   // px-half (0,1)

#pragma unroll 1
  for (int mi = 0; mi < 3; ++mi) {
    int m0 = mbase + mi * 64;
    f32x4 acc[2][2];
#pragma unroll
    for (int mf = 0; mf < 2; ++mf)
#pragma unroll
      for (int nf = 0; nf < 2; ++nf) acc[mf][nf] = (f32x4){0.f, 0.f, 0.f, 0.f};

#pragma unroll
    for (int k0 = 0; k0 < C_; k0 += 32) {
      short8v a[2], bfr[2];
#pragma unroll
      for (int mf = 0; mf < 2; ++mf)
        a[mf] = *(const short8v*)(wtb + (m0 + wr * 32 + mf * 16 + col) * C_ + k0 + kg * 8);
#pragma unroll
      for (int nf = 0; nf < 2; ++nf) {
        int brow = wc * 32 + nf * 16 + col;
        int kb = (k0 + kg * 8) * 2;
        bfr[nf] = *(const short8v*)(sbase + brow * 384 + (kb ^ ((brow & 7) << 4)));
      }
#pragma unroll
      for (int mf = 0; mf < 2; ++mf)
#pragma unroll
        for (int nf = 0; nf < 2; ++nf)
          acc[mf][nf] = __builtin_amdgcn_mfma_f32_16x16x32_bf16(a[mf], bfr[nf], acc[mf][nf], 0, 0, 0);
    }

#pragma unroll
    for (int mf = 0; mf < 2; ++mf) {
#pragma unroll
      for (int nf = 0; nf < 2; ++nf) {
        int p = n0 + wc * 32 + nf * 16 + col;
        int bb = p / HW_;
        int hw = p - bb * HW_;
#pragma unroll
        for (int reg = 0; reg < 4; ++reg) {
          int o = m0 + wr * 32 + mf * 16 + kg * 4 + reg;
          float a = acc[mf][nf][reg];
          float r = a * fminf(fmaxf(a + 3.f, 0.f), 6.f) * (1.f / 6.f);
          out[((size_t)bb * O_ + o) * HW_ + hw] = r;
        }
      }
    }
  }
}

extern "C" void kernel_launch(void* const* d_in, const int* in_sizes, int n_in,
                              void* d_out, int out_size, void* d_ws, size_t ws_size,
                              hipStream_t stream) {
  const float* x = (const float*)d_in[0];
  const float* og_dw = (const float*)d_in[1];
  const float* og_pw = (const float*)d_in[2];
  const float* dcn_w = (const float*)d_in[3];
  const float* pw_w = (const float*)d_in[4];
  float* out = (float*)d_out;

  float* ws = (float*)d_ws;
  float* offp3 = ws;                                     // 3*B*18*HW f32
  float* dcnT_g = offp3 + 3 * (size_t)B_ * NOFF * HW_;   // 9*C f32
  unsigned short* y1t = (unsigned short*)(dcnT_g + 9 * C_);  // NPIX*C bf16
  unsigned short* wtb = y1t + (size_t)NPIX * C_;         // O*C bf16
  unsigned short* x_t = wtb + (size_t)O_ * C_;           // NPIX*C bf16
  unsigned short* w2b = x_t + (size_t)NPIX * C_;         // 32*1728 bf16

  k_prep<<<(O_ * C_ + 32 * K2 + 9 * C_ + TPB - 1) / TPB, TPB, 0, stream>>>(
      og_dw, og_pw, pw_w, dcn_w, wtb, w2b, dcnT_g);
  k_xt<<<dim3(HW_ / 64, B_), TPB, 0, stream>>>(x, x_t);
  k_off2s<<<dim3(W_ / 8, H_ / 8, B_ * 3), TPB, 0, stream>>>(x_t, w2b, offp3);
  k_deform11<<<196 * 4 * B_ / 8, 512, 0, stream>>>(x_t, offp3, dcnT_g, y1t);
  k_gemm4<<<dim3(NPIX / 64, 2), TPB, 0, stream>>>(y1t, wtb, out);
}

// Round 17
// 79.801 us; speedup vs baseline: 1.6900x; 1.0489x over previous
//
#include <hip/hip_runtime.h>
#include <hip/hip_fp16.h>

#define TPB 256
constexpr int B_ = 8, C_ = 192, H_ = 56, W_ = 56, O_ = 384;
constexpr int HW_ = H_ * W_;          // 3136
constexpr int NOFF = 18;              // 9 taps * 2 (dy,dx)
constexpr int NPIX = B_ * HW_;        // 25088 = 196 * 128
constexpr int K2 = 9 * C_;            // 1728 combined-conv K

typedef __attribute__((ext_vector_type(8))) short short8v;
typedef __attribute__((ext_vector_type(4))) float f32x4;
typedef __attribute__((ext_vector_type(2))) float f32x2;

__device__ inline unsigned short f2bf(float f) {
  unsigned u = __builtin_bit_cast(unsigned, f);
  unsigned r = (u + 0x7fffu + ((u >> 16) & 1u)) >> 16;
  return (unsigned short)r;
}
__device__ inline float bflo(unsigned u) {
  return __builtin_bit_cast(float, u << 16);
}
__device__ inline float bfhi(unsigned u) {
  return __builtin_bit_cast(float, u & 0xffff0000u);
}

// ---- K_XTP: x transpose->bf16 AND all weight prep in one launch ----------
// prep work (wtb, w2b, dcnT_g) is independent of xt work; distributing it
// over this kernel's 392x256 threads removes one kernel launch + gap.
__global__ __launch_bounds__(TPB) void k_xtp(const float* __restrict__ x,
                                             const float* __restrict__ og_dw,
                                             const float* __restrict__ og_pw,
                                             const float* __restrict__ pw,
                                             const float* __restrict__ dcn,
                                             unsigned short* __restrict__ xt,
                                             unsigned short* __restrict__ wtb,
                                             unsigned short* __restrict__ w2b,
                                             float* __restrict__ dcnT_g) {
  __shared__ unsigned short tile[64 * 198];
  int tid = threadIdx.x;
  int P0 = blockIdx.x * 64;
  int b = blockIdx.y;

  // --- distributed prep: 130752 items over 100352 threads (2 iters) ---
  int gid = (blockIdx.y * 49 + blockIdx.x) * TPB + tid;
#pragma unroll
  for (int it = 0; it < 2; ++it) {
    int i = gid + it * (49 * 8 * TPB);
    if (i < O_ * C_) {
      wtb[i] = f2bf(pw[i]);
    } else if (i < O_ * C_ + 32 * K2) {
      int j = i - O_ * C_;
      int o = j / K2, k = j - o * K2;
      int tap = k / C_, c = k - tap * C_;
      float v = 0.f;
      if (o < NOFF) v = og_pw[o * C_ + c] * og_dw[c * 9 + tap];
      w2b[j] = f2bf(v);
    } else if (i < O_ * C_ + 32 * K2 + 9 * C_) {
      int j2 = i - O_ * C_ - 32 * K2;
      int k = j2 / C_, c = j2 - k * C_;
      dcnT_g[j2] = dcn[c * 9 + k];
    }
  }

  // --- xt transpose body (unchanged) ---
#pragma unroll
  for (int i = 0; i < 48; ++i) {
    int idx = i * TPB + tid;
    int px = idx & 63;
    int c = idx >> 6;
    float v = x[((size_t)(b * C_ + c)) * HW_ + P0 + px];
    tile[px * 198 + c] = f2bf(v);
  }
  __syncthreads();
  unsigned* xtu = (unsigned*)xt;
#pragma unroll
  for (int i = 0; i < 24; ++i) {
    int d = i * TPB + tid;            // dword index in 64*96
    int px = d / 96;
    int c2 = d - px * 96;
    unsigned v = *(const unsigned*)&tile[px * 198 + c2 * 2];
    xtu[((size_t)b * HW_ + P0 + px) * 96 + c2] = v;
  }
}

// ---- K_OFF2s: offset conv, K-split by tap-row; batch->XCD swizzled -------
__global__ __launch_bounds__(TPB) void k_off2s(const unsigned short* __restrict__ xt,
                                               const unsigned short* __restrict__ w2b,
                                               float* __restrict__ offp3) {
  __shared__ __align__(16) unsigned short hal[80 * 192];  // 30.7 KB
  int tid = threadIdx.x;
  int w0 = blockIdx.x * 8;
  int h0 = blockIdx.y * 8;
  int bz = blockIdx.z;
  int b = bz & 7;                     // XCD-locality: batch b -> XCD b
  int s = bz >> 3;                    // tap-row split; dy = s-1
  int dy = s - 1;

  char* sb = (char*)hal;
  const uint4* xu4 = (const uint4*)xt;  // 16B = 8ch; 24 units per pixel
#pragma unroll
  for (int i = 0; i < 8; ++i) {
    int u = i * TPB + tid;            // 80 pos x 24 uint4 = 1920
    if (u < 1920) {
      int pos = u / 24, c4 = u - pos * 24;
      int ry = pos / 10;
      int gy = h0 + ry + dy;
      int gx = w0 - 1 + (pos - ry * 10);
      uint4 v = {0u, 0u, 0u, 0u};
      if ((unsigned)gy < (unsigned)H_ && (unsigned)gx < (unsigned)W_)
        v = xu4[((size_t)b * HW_ + gy * W_ + gx) * 24 + c4];
      *(uint4*)(sb + pos * 384 + ((c4 * 16) ^ ((pos & 7) << 4))) = v;
    }
  }
  __syncthreads();

  int wid = tid >> 6;
  int lane = tid & 63;
  int col = lane & 15;
  int kg = lane >> 4;
  int gpx = wid * 16 + col;           // tile-local pixel 0..63
  int py = gpx >> 3, px_ = gpx & 7;

  f32x4 acc0 = (f32x4){0.f, 0.f, 0.f, 0.f};
  f32x4 acc1 = (f32x4){0.f, 0.f, 0.f, 0.f};

#pragma unroll
  for (int j = 0; j < 3; ++j) {       // dx = j-1; tap = 3s+j
    int tap = 3 * s + j;
    int pos = py * 10 + px_ + j;
    int pbase = pos * 384;
    int psw = (pos & 7) << 4;
    const unsigned short* wrow = w2b + tap * C_ + kg * 8;
#pragma unroll
    for (int cs = 0; cs < 6; ++cs) {
      short8v bfrag = *(const short8v*)(sb + pbase + ((cs * 64 + kg * 16) ^ psw));
      short8v a0 = *(const short8v*)(wrow + cs * 32 + (size_t)col * K2);
      short8v a1 = *(const short8v*)(wrow + cs * 32 + (size_t)(16 + col) * K2);
      acc0 = __builtin_amdgcn_mfma_f32_16x16x32_bf16(a0, bfrag, acc0, 0, 0, 0);
      acc1 = __builtin_amdgcn_mfma_f32_16x16x32_bf16(a1, bfrag, acc1, 0, 0, 0);
    }
  }

  float* ob = offp3 + (size_t)(s * B_ + b) * NOFF * HW_ + (h0 + py) * W_ + w0 + px_;
#pragma unroll
  for (int reg = 0; reg < 4; ++reg) {
    int o0 = kg * 4 + reg;            // 0..15, always < 18
    ob[(size_t)o0 * HW_] = acc0[reg];
    int o1 = 16 + kg * 4 + reg;       // valid only for 16,17
    if (o1 < NOFF) ob[(size_t)o1 * HW_] = acc1[reg];
  }
}

// ---- K3: deform+dcn; 8x4 tile, 512 thr, LINEAR halo, f32 wtab, pk-f32 ----
__global__ __launch_bounds__(512, 8) void k_deform11(const unsigned short* __restrict__ xt,
                                                     const float* __restrict__ offp3,
                                                     const float* __restrict__ dcnT_g,
                                                     unsigned short* __restrict__ y1t) {
  __shared__ __align__(16) unsigned short hal[117 * 192];  // 44.9 KB linear
  __shared__ __align__(16) f32x4 w4tab[288];               // 4.6 KB
  __shared__ int postab[288];                              // 1.2 KB
  int tid = threadIdx.x;
  int bid = blockIdx.x;
  int b = bid & 7;                    // XCD-locality: batch b -> XCD b
  int tile = bid >> 3;                // 0..97
  int ty = tile / 7;
  int h0 = ty * 4;
  int w0 = (tile - ty * 7) * 8;

  uint4* halu4 = (uint4*)hal;
  const uint4* xu4 = (const uint4*)xt;
#pragma unroll
  for (int i = 0; i < 6; ++i) {
    int u = i * 512 + tid;            // 117 pos x 24 uint4 = 2808
    if (u < 2808) {
      int pos = u / 24;
      int ly = pos / 13, lx = pos - ly * 13;
      int gy = h0 - 2 + ly, gx = w0 - 2 + lx;
      uint4 v = {0u, 0u, 0u, 0u};
      if ((unsigned)gy < (unsigned)H_ && (unsigned)gx < (unsigned)W_)
        v = xu4[((size_t)b * HW_ + gy * W_ + gx) * 24 + (u - pos * 24)];
      halu4[u] = v;                   // linear: pos*24 + c4 == u
    }
  }

  if (tid < 288) {                    // 32 px x 9 taps
    int pxl = tid / 9, tap = tid - pxl * 9;
    int py = pxl >> 3, pxx = pxl & 7;
    int h = h0 + py, w = w0 + pxx;
    int hw = h * W_ + w;
    const float* p0 = offp3 + (size_t)b * NOFF * HW_ + hw;
    const float* p1 = p0 + (size_t)B_ * NOFF * HW_;
    const float* p2 = p1 + (size_t)B_ * NOFF * HW_;
    int t3 = tap / 3;
    int ky = t3 - 1, kx = tap - t3 * 3 - 1;
    size_t ody = (size_t)(2 * tap) * HW_;
    size_t odx = ody + HW_;
    float dyv = p0[ody] + p1[ody] + p2[ody];
    float dxv = p0[odx] + p1[odx] + p2[odx];
    dyv = fminf(fmaxf(dyv, -1.f), 1.f);
    dxv = fminf(fmaxf(dxv, -1.f), 1.f);
    float ys = (float)(h + ky) + dyv;
    float xs = (float)(w + kx) + dxv;
    float y0f = floorf(ys), x0f = floorf(xs);
    float tyf = ys - y0f, txf = xs - x0f;
    int y0 = (int)y0f, x0 = (int)x0f;
    float fy0 = ((unsigned)y0 < (unsigned)H_) ? 1.f : 0.f;
    float fy1 = ((unsigned)(y0 + 1) < (unsigned)H_) ? 1.f : 0.f;
    float fx0 = ((unsigned)x0 < (unsigned)W_) ? 1.f : 0.f;
    float fx1 = ((unsigned)(x0 + 1) < (unsigned)W_) ? 1.f : 0.f;
    float omty = 1.f - tyf, omtx = 1.f - txf;
    f32x4 w4;
    w4.x = omty * omtx * fy0 * fx0;
    w4.y = omty * txf * fy0 * fx1;
    w4.z = tyf * omtx * fy1 * fx0;
    w4.w = tyf * txf * fy1 * fx1;
    w4tab[tid] = w4;
    postab[tid] = (y0 - (h0 - 2)) * 13 + (x0 - (w0 - 2));
  }
  __syncthreads();

  int pl = tid >> 4;                  // 0..31: local pixel
  int lg = tid & 15;
  int py = pl >> 3, pxx = pl & 7;
  int hw = (h0 + py) * W_ + w0 + pxx;
  int co0 = lg * 4;

  f32x2 acc2[6];
#pragma unroll
  for (int j = 0; j < 6; ++j) acc2[j] = (f32x2){0.f, 0.f};

#pragma unroll
  for (int tap = 0; tap < 9; ++tap) {
    f32x4 w4 = w4tab[pl * 9 + tap];
    int posA = postab[pl * 9 + tap];
    const unsigned short* base = hal + posA * 192 + co0;
#pragma unroll
    for (int rep = 0; rep < 3; ++rep) {
      int co = rep * 64;
      uint2 u00 = *(const uint2*)(base + co);
      uint2 u01 = *(const uint2*)(base + 192 + co);
      uint2 u10 = *(const uint2*)(base + 13 * 192 + co);
      uint2 u11 = *(const uint2*)(base + 14 * 192 + co);
      f32x4 dw = *(const f32x4*)&dcnT_g[tap * C_ + co0 + co];
      f32x2 v00l = (f32x2){bflo(u00.x), bfhi(u00.x)};
      f32x2 v01l = (f32x2){bflo(u01.x), bfhi(u01.x)};
      f32x2 v10l = (f32x2){bflo(u10.x), bfhi(u10.x)};
      f32x2 v11l = (f32x2){bflo(u11.x), bfhi(u11.x)};
      f32x2 v00h = (f32x2){bflo(u00.y), bfhi(u00.y)};
      f32x2 v01h = (f32x2){bflo(u01.y), bfhi(u01.y)};
      f32x2 v10h = (f32x2){bflo(u10.y), bfhi(u10.y)};
      f32x2 v11h = (f32x2){bflo(u11.y), bfhi(u11.y)};
      f32x2 sl = v00l * w4.x + v01l * w4.y + v10l * w4.z + v11l * w4.w;
      f32x2 sh = v00h * w4.x + v01h * w4.y + v10h * w4.z + v11h * w4.w;
      acc2[rep * 2 + 0] += sl * (f32x2){dw.x, dw.y};
      acc2[rep * 2 + 1] += sh * (f32x2){dw.z, dw.w};
    }
  }

  size_t ob = ((size_t)b * HW_ + hw) * C_ + co0;
#pragma unroll
  for (int rep = 0; rep < 3; ++rep) {
    uint2 pk;
    pk.x = (unsigned)f2bf(acc2[rep * 2][0]) | ((unsigned)f2bf(acc2[rep * 2][1]) << 16);
    pk.y = (unsigned)f2bf(acc2[rep * 2 + 1][0]) | ((unsigned)f2bf(acc2[rep * 2 + 1][1]) << 16);
    *(uint2*)(y1t + ob + rep * 64) = pk;
  }
}

// ---- K4: 64 px x 192 O; batch->XCD aligned with deform's y1t writes ------
// bid: b = bid&7 (same mapping as k_deform11) -> y1t reads hit local L2.
__global__ __launch_bounds__(TPB) void k_gemm5(const unsigned short* __restrict__ y1t,
                                               const unsigned short* __restrict__ wtb,
                                               float* __restrict__ out) {
  __shared__ __align__(16) unsigned short bsm[64 * 192];  // 24 KB
  int tid = threadIdx.x;
  int bid = blockIdx.x;
  int b = bid & 7;                    // XCD-locality: batch b -> XCD b
  int r = bid >> 3;                   // 0..97
  int mhalf = r / 49;
  int tile = r - mhalf * 49;
  int n0 = b * HW_ + tile * 64;
  int mbase = mhalf * 192;

  const uint4* src = (const uint4*)(y1t + (size_t)n0 * C_);  // 64*24 uint4
  char* sbase = (char*)bsm;
#pragma unroll
  for (int i = 0; i < 6; ++i) {
    int u = i * TPB + tid;            // 1536 units
    int row = u / 24;
    int c4 = u - row * 24;
    uint4 v = src[u];
    *(uint4*)(sbase + row * 384 + ((c4 * 16) ^ ((row & 7) << 4))) = v;
  }
  __syncthreads();

  int wid = tid >> 6;
  int lane = tid & 63;
  int col = lane & 15;
  int kg = lane >> 4;
  int wr = wid >> 1;                  // O-half (0,1)
  int wc = wid & 1;                   // px-half (0,1)

#pragma unroll 1
  for (int mi = 0; mi < 3; ++mi) {
    int m0 = mbase + mi * 64;
    f32x4 acc[2][2];
#pragma unroll
    for (int mf = 0; mf < 2; ++mf)
#pragma unroll
      for (int nf = 0; nf < 2; ++nf) acc[mf][nf] = (f32x4){0.f, 0.f, 0.f, 0.f};

#pragma unroll
    for (int k0 = 0; k0 < C_; k0 += 32) {
      short8v a[2], bfr[2];
#pragma unroll
      for (int mf = 0; mf < 2; ++mf)
        a[mf] = *(const short8v*)(wtb + (m0 + wr * 32 + mf * 16 + col) * C_ + k0 + kg * 8);
#pragma unroll
      for (int nf = 0; nf < 2; ++nf) {
        int brow = wc * 32 + nf * 16 + col;
        int kb = (k0 + kg * 8) * 2;
        bfr[nf] = *(const short8v*)(sbase + brow * 384 + (kb ^ ((brow & 7) << 4)));
      }
#pragma unroll
      for (int mf = 0; mf < 2; ++mf)
#pragma unroll
        for (int nf = 0; nf < 2; ++nf)
          acc[mf][nf] = __builtin_amdgcn_mfma_f32_16x16x32_bf16(a[mf], bfr[nf], acc[mf][nf], 0, 0, 0);
    }

#pragma unroll
    for (int mf = 0; mf < 2; ++mf) {
#pragma unroll
      for (int nf = 0; nf < 2; ++nf) {
        int p = n0 + wc * 32 + nf * 16 + col;
        int hw = p - b * HW_;
#pragma unroll
        for (int reg = 0; reg < 4; ++reg) {
          int o = m0 + wr * 32 + mf * 16 + kg * 4 + reg;
          float a = acc[mf][nf][reg];
          float rr = a * fminf(fmaxf(a + 3.f, 0.f), 6.f) * (1.f / 6.f);
          out[((size_t)b * O_ + o) * HW_ + hw] = rr;
        }
      }
    }
  }
}

extern "C" void kernel_launch(void* const* d_in, const int* in_sizes, int n_in,
                              void* d_out, int out_size, void* d_ws, size_t ws_size,
                              hipStream_t stream) {
  const float* x = (const float*)d_in[0];
  const float* og_dw = (const float*)d_in[1];
  const float* og_pw = (const float*)d_in[2];
  const float* dcn_w = (const float*)d_in[3];
  const float* pw_w = (const float*)d_in[4];
  float* out = (float*)d_out;

  float* ws = (float*)d_ws;
  float* offp3 = ws;                                     // 3*B*18*HW f32
  float* dcnT_g = offp3 + 3 * (size_t)B_ * NOFF * HW_;   // 9*C f32
  unsigned short* y1t = (unsigned short*)(dcnT_g + 9 * C_);  // NPIX*C bf16
  unsigned short* wtb = y1t + (size_t)NPIX * C_;         // O*C bf16
  unsigned short* x_t = wtb + (size_t)O_ * C_;           // NPIX*C bf16
  unsigned short* w2b = x_t + (size_t)NPIX * C_;         // 32*1728 bf16

  k_xtp<<<dim3(HW_ / 64, B_), TPB, 0, stream>>>(x, og_dw, og_pw, pw_w, dcn_w,
                                                x_t, wtb, w2b, dcnT_g);
  k_off2s<<<dim3(W_ / 8, H_ / 8, B_ * 3), TPB, 0, stream>>>(x_t, w2b, offp3);
  k_deform11<<<196 * 4 * B_ / 8, 512, 0, stream>>>(x_t, offp3, dcnT_g, y1t);
  k_gemm5<<<NPIX / 64 * 2, TPB, 0, stream>>>(y1t, wtb, out);
}

// Round 18
// 79.735 us; speedup vs baseline: 1.6914x; 1.0008x over previous
//
#include <hip/hip_runtime.h>
#include <hip/hip_fp16.h>

#define TPB 256
constexpr int B_ = 8, C_ = 192, H_ = 56, W_ = 56, O_ = 384;
constexpr int HW_ = H_ * W_;          // 3136
constexpr int NOFF = 18;              // 9 taps * 2 (dy,dx)
constexpr int NPIX = B_ * HW_;        // 25088 = 196 * 128
constexpr int K2 = 9 * C_;            // 1728 combined-conv K

typedef __attribute__((ext_vector_type(8))) short short8v;
typedef __attribute__((ext_vector_type(4))) float f32x4;
typedef __attribute__((ext_vector_type(2))) float f32x2;

__device__ inline unsigned short f2bf(float f) {
  unsigned u = __builtin_bit_cast(unsigned, f);
  unsigned r = (u + 0x7fffu + ((u >> 16) & 1u)) >> 16;
  return (unsigned short)r;
}
__device__ inline float bflo(unsigned u) {
  return __builtin_bit_cast(float, u << 16);
}
__device__ inline float bfhi(unsigned u) {
  return __builtin_bit_cast(float, u & 0xffff0000u);
}

// ---- K_XTP: x transpose->bf16 AND all weight prep in one launch ----------
__global__ __launch_bounds__(TPB) void k_xtp(const float* __restrict__ x,
                                             const float* __restrict__ og_dw,
                                             const float* __restrict__ og_pw,
                                             const float* __restrict__ pw,
                                             const float* __restrict__ dcn,
                                             unsigned short* __restrict__ xt,
                                             unsigned short* __restrict__ wtb,
                                             unsigned short* __restrict__ w2b,
                                             float* __restrict__ dcnT_g) {
  __shared__ unsigned short tile[64 * 198];
  int tid = threadIdx.x;
  int P0 = blockIdx.x * 64;
  int b = blockIdx.y;

  // --- distributed prep: 130752 items over 100352 threads (2 iters) ---
  int gid = (blockIdx.y * 49 + blockIdx.x) * TPB + tid;
#pragma unroll
  for (int it = 0; it < 2; ++it) {
    int i = gid + it * (49 * 8 * TPB);
    if (i < O_ * C_) {
      wtb[i] = f2bf(pw[i]);
    } else if (i < O_ * C_ + 32 * K2) {
      int j = i - O_ * C_;
      int o = j / K2, k = j - o * K2;
      int tap = k / C_, c = k - tap * C_;
      float v = 0.f;
      if (o < NOFF) v = og_pw[o * C_ + c] * og_dw[c * 9 + tap];
      w2b[j] = f2bf(v);
    } else if (i < O_ * C_ + 32 * K2 + 9 * C_) {
      int j2 = i - O_ * C_ - 32 * K2;
      int k = j2 / C_, c = j2 - k * C_;
      dcnT_g[j2] = dcn[c * 9 + k];
    }
  }

  // --- xt transpose body (unchanged) ---
#pragma unroll
  for (int i = 0; i < 48; ++i) {
    int idx = i * TPB + tid;
    int px = idx & 63;
    int c = idx >> 6;
    float v = x[((size_t)(b * C_ + c)) * HW_ + P0 + px];
    tile[px * 198 + c] = f2bf(v);
  }
  __syncthreads();
  unsigned* xtu = (unsigned*)xt;
#pragma unroll
  for (int i = 0; i < 24; ++i) {
    int d = i * TPB + tid;            // dword index in 64*96
    int px = d / 96;
    int c2 = d - px * 96;
    unsigned v = *(const unsigned*)&tile[px * 198 + c2 * 2];
    xtu[((size_t)b * HW_ + P0 + px) * 96 + c2] = v;
  }
}

// ---- K_OFF2s: offset conv, K-split by tap-row; batch->XCD swizzled -------
__global__ __launch_bounds__(TPB) void k_off2s(const unsigned short* __restrict__ xt,
                                               const unsigned short* __restrict__ w2b,
                                               float* __restrict__ offp3) {
  __shared__ __align__(16) unsigned short hal[80 * 192];  // 30.7 KB
  int tid = threadIdx.x;
  int w0 = blockIdx.x * 8;
  int h0 = blockIdx.y * 8;
  int bz = blockIdx.z;
  int b = bz & 7;                     // XCD-locality: batch b -> XCD b
  int s = bz >> 3;                    // tap-row split; dy = s-1
  int dy = s - 1;

  char* sb = (char*)hal;
  const uint4* xu4 = (const uint4*)xt;  // 16B = 8ch; 24 units per pixel
#pragma unroll
  for (int i = 0; i < 8; ++i) {
    int u = i * TPB + tid;            // 80 pos x 24 uint4 = 1920
    if (u < 1920) {
      int pos = u / 24, c4 = u - pos * 24;
      int ry = pos / 10;
      int gy = h0 + ry + dy;
      int gx = w0 - 1 + (pos - ry * 10);
      uint4 v = {0u, 0u, 0u, 0u};
      if ((unsigned)gy < (unsigned)H_ && (unsigned)gx < (unsigned)W_)
        v = xu4[((size_t)b * HW_ + gy * W_ + gx) * 24 + c4];
      *(uint4*)(sb + pos * 384 + ((c4 * 16) ^ ((pos & 7) << 4))) = v;
    }
  }
  __syncthreads();

  int wid = tid >> 6;
  int lane = tid & 63;
  int col = lane & 15;
  int kg = lane >> 4;
  int gpx = wid * 16 + col;           // tile-local pixel 0..63
  int py = gpx >> 3, px_ = gpx & 7;

  f32x4 acc0 = (f32x4){0.f, 0.f, 0.f, 0.f};
  f32x4 acc1 = (f32x4){0.f, 0.f, 0.f, 0.f};

#pragma unroll
  for (int j = 0; j < 3; ++j) {       // dx = j-1; tap = 3s+j
    int tap = 3 * s + j;
    int pos = py * 10 + px_ + j;
    int pbase = pos * 384;
    int psw = (pos & 7) << 4;
    const unsigned short* wrow = w2b + tap * C_ + kg * 8;
#pragma unroll
    for (int cs = 0; cs < 6; ++cs) {
      short8v bfrag = *(const short8v*)(sb + pbase + ((cs * 64 + kg * 16) ^ psw));
      short8v a0 = *(const short8v*)(wrow + cs * 32 + (size_t)col * K2);
      short8v a1 = *(const short8v*)(wrow + cs * 32 + (size_t)(16 + col) * K2);
      acc0 = __builtin_amdgcn_mfma_f32_16x16x32_bf16(a0, bfrag, acc0, 0, 0, 0);
      acc1 = __builtin_amdgcn_mfma_f32_16x16x32_bf16(a1, bfrag, acc1, 0, 0, 0);
    }
  }

  float* ob = offp3 + (size_t)(s * B_ + b) * NOFF * HW_ + (h0 + py) * W_ + w0 + px_;
#pragma unroll
  for (int reg = 0; reg < 4; ++reg) {
    int o0 = kg * 4 + reg;            // 0..15, always < 18
    ob[(size_t)o0 * HW_] = acc0[reg];
    int o1 = 16 + kg * 4 + reg;       // valid only for 16,17
    if (o1 < NOFF) ob[(size_t)o1 * HW_] = acc1[reg];
  }
}

// ---- K3: deform+dcn; 8x4 tile, 512 thr, LINEAR halo, f32 wtab, pk-f32 ----
// launch_bounds (512,4): 128-VGPR cap -> no scratch spill (the (512,8)
// 64-VGPR cap forced ~25 spilled regs through per-lane scratch/HBM).
__global__ __launch_bounds__(512, 4) void k_deform11(const unsigned short* __restrict__ xt,
                                                     const float* __restrict__ offp3,
                                                     const float* __restrict__ dcnT_g,
                                                     unsigned short* __restrict__ y1t) {
  __shared__ __align__(16) unsigned short hal[117 * 192];  // 44.9 KB linear
  __shared__ __align__(16) f32x4 w4tab[288];               // 4.6 KB
  __shared__ int postab[288];                              // 1.2 KB
  int tid = threadIdx.x;
  int bid = blockIdx.x;
  int b = bid & 7;                    // XCD-locality: batch b -> XCD b
  int tile = bid >> 3;                // 0..97
  int ty = tile / 7;
  int h0 = ty * 4;
  int w0 = (tile - ty * 7) * 8;

  uint4* halu4 = (uint4*)hal;
  const uint4* xu4 = (const uint4*)xt;
#pragma unroll
  for (int i = 0; i < 6; ++i) {
    int u = i * 512 + tid;            // 117 pos x 24 uint4 = 2808
    if (u < 2808) {
      int pos = u / 24;
      int ly = pos / 13, lx = pos - ly * 13;
      int gy = h0 - 2 + ly, gx = w0 - 2 + lx;
      uint4 v = {0u, 0u, 0u, 0u};
      if ((unsigned)gy < (unsigned)H_ && (unsigned)gx < (unsigned)W_)
        v = xu4[((size_t)b * HW_ + gy * W_ + gx) * 24 + (u - pos * 24)];
      halu4[u] = v;                   // linear: pos*24 + c4 == u
    }
  }

  if (tid < 288) {                    // 32 px x 9 taps
    int pxl = tid / 9, tap = tid - pxl * 9;
    int py = pxl >> 3, pxx = pxl & 7;
    int h = h0 + py, w = w0 + pxx;
    int hw = h * W_ + w;
    const float* p0 = offp3 + (size_t)b * NOFF * HW_ + hw;
    const float* p1 = p0 + (size_t)B_ * NOFF * HW_;
    const float* p2 = p1 + (size_t)B_ * NOFF * HW_;
    int t3 = tap / 3;
    int ky = t3 - 1, kx = tap - t3 * 3 - 1;
    size_t ody = (size_t)(2 * tap) * HW_;
    size_t odx = ody + HW_;
    float dyv = p0[ody] + p1[ody] + p2[ody];
    float dxv = p0[odx] + p1[odx] + p2[odx];
    dyv = fminf(fmaxf(dyv, -1.f), 1.f);
    dxv = fminf(fmaxf(dxv, -1.f), 1.f);
    float ys = (float)(h + ky) + dyv;
    float xs = (float)(w + kx) + dxv;
    float y0f = floorf(ys), x0f = floorf(xs);
    float tyf = ys - y0f, txf = xs - x0f;
    int y0 = (int)y0f, x0 = (int)x0f;
    float fy0 = ((unsigned)y0 < (unsigned)H_) ? 1.f : 0.f;
    float fy1 = ((unsigned)(y0 + 1) < (unsigned)H_) ? 1.f : 0.f;
    float fx0 = ((unsigned)x0 < (unsigned)W_) ? 1.f : 0.f;
    float fx1 = ((unsigned)(x0 + 1) < (unsigned)W_) ? 1.f : 0.f;
    float omty = 1.f - tyf, omtx = 1.f - txf;
    f32x4 w4;
    w4.x = omty * omtx * fy0 * fx0;
    w4.y = omty * txf * fy0 * fx1;
    w4.z = tyf * omtx * fy1 * fx0;
    w4.w = tyf * txf * fy1 * fx1;
    w4tab[tid] = w4;
    postab[tid] = (y0 - (h0 - 2)) * 13 + (x0 - (w0 - 2));
  }
  __syncthreads();

  int pl = tid >> 4;                  // 0..31: local pixel
  int lg = tid & 15;
  int py = pl >> 3, pxx = pl & 7;
  int hw = (h0 + py) * W_ + w0 + pxx;
  int co0 = lg * 4;

  f32x2 acc2[6];
#pragma unroll
  for (int j = 0; j < 6; ++j) acc2[j] = (f32x2){0.f, 0.f};

#pragma unroll
  for (int tap = 0; tap < 9; ++tap) {
    f32x4 w4 = w4tab[pl * 9 + tap];
    int posA = postab[pl * 9 + tap];
    const unsigned short* base = hal + posA * 192 + co0;
#pragma unroll
    for (int rep = 0; rep < 3; ++rep) {
      int co = rep * 64;
      uint2 u00 = *(const uint2*)(base + co);
      uint2 u01 = *(const uint2*)(base + 192 + co);
      uint2 u10 = *(const uint2*)(base + 13 * 192 + co);
      uint2 u11 = *(const uint2*)(base + 14 * 192 + co);
      f32x4 dw = *(const f32x4*)&dcnT_g[tap * C_ + co0 + co];
      f32x2 v00l = (f32x2){bflo(u00.x), bfhi(u00.x)};
      f32x2 v01l = (f32x2){bflo(u01.x), bfhi(u01.x)};
      f32x2 v10l = (f32x2){bflo(u10.x), bfhi(u10.x)};
      f32x2 v11l = (f32x2){bflo(u11.x), bfhi(u11.x)};
      f32x2 v00h = (f32x2){bflo(u00.y), bfhi(u00.y)};
      f32x2 v01h = (f32x2){bflo(u01.y), bfhi(u01.y)};
      f32x2 v10h = (f32x2){bflo(u10.y), bfhi(u10.y)};
      f32x2 v11h = (f32x2){bflo(u11.y), bfhi(u11.y)};
      f32x2 sl = v00l * w4.x + v01l * w4.y + v10l * w4.z + v11l * w4.w;
      f32x2 sh = v00h * w4.x + v01h * w4.y + v10h * w4.z + v11h * w4.w;
      acc2[rep * 2 + 0] += sl * (f32x2){dw.x, dw.y};
      acc2[rep * 2 + 1] += sh * (f32x2){dw.z, dw.w};
    }
  }

  size_t ob = ((size_t)b * HW_ + hw) * C_ + co0;
#pragma unroll
  for (int rep = 0; rep < 3; ++rep) {
    uint2 pk;
    pk.x = (unsigned)f2bf(acc2[rep * 2][0]) | ((unsigned)f2bf(acc2[rep * 2][1]) << 16);
    pk.y = (unsigned)f2bf(acc2[rep * 2 + 1][0]) | ((unsigned)f2bf(acc2[rep * 2 + 1][1]) << 16);
    *(uint2*)(y1t + ob + rep * 64) = pk;
  }
}

// ---- K4: 64 px x 192 O; batch->XCD aligned with deform's y1t writes ------
__global__ __launch_bounds__(TPB) void k_gemm5(const unsigned short* __restrict__ y1t,
                                               const unsigned short* __restrict__ wtb,
                                               float* __restrict__ out) {
  __shared__ __align__(16) unsigned short bsm[64 * 192];  // 24 KB
  int tid = threadIdx.x;
  int bid = blockIdx.x;
  int b = bid & 7;                    // XCD-locality: batch b -> XCD b
  int r = bid >> 3;                   // 0..97
  int mhalf = r / 49;
  int tile = r - mhalf * 49;
  int n0 = b * HW_ + tile * 64;
  int mbase = mhalf * 192;

  const uint4* src = (const uint4*)(y1t + (size_t)n0 * C_);  // 64*24 uint4
  char* sbase = (char*)bsm;
#pragma unroll
  for (int i = 0; i < 6; ++i) {
    int u = i * TPB + tid;            // 1536 units
    int row = u / 24;
    int c4 = u - row * 24;
    uint4 v = src[u];
    *(uint4*)(sbase + row * 384 + ((c4 * 16) ^ ((row & 7) << 4))) = v;
  }
  __syncthreads();

  int wid = tid >> 6;
  int lane = tid & 63;
  int col = lane & 15;
  int kg = lane >> 4;
  int wr = wid >> 1;                  // O-half (0,1)
  int wc = wid & 1;                   // px-half (0,1)

#pragma unroll 1
  for (int mi = 0; mi < 3; ++mi) {
    int m0 = mbase + mi * 64;
    f32x4 acc[2][2];
#pragma unroll
    for (int mf = 0; mf < 2; ++mf)
#pragma unroll
      for (int nf = 0; nf < 2; ++nf) acc[mf][nf] = (f32x4){0.f, 0.f, 0.f, 0.f};

#pragma unroll
    for (int k0 = 0; k0 < C_; k0 += 32) {
      short8v a[2], bfr[2];
#pragma unroll
      for (int mf = 0; mf < 2; ++mf)
        a[mf] = *(const short8v*)(wtb + (m0 + wr * 32 + mf * 16 + col) * C_ + k0 + kg * 8);
#pragma unroll
      for (int nf = 0; nf < 2; ++nf) {
        int brow = wc * 32 + nf * 16 + col;
        int kb = (k0 + kg * 8) * 2;
        bfr[nf] = *(const short8v*)(sbase + brow * 384 + (kb ^ ((brow & 7) << 4)));
      }
#pragma unroll
      for (int mf = 0; mf < 2; ++mf)
#pragma unroll
        for (int nf = 0; nf < 2; ++nf)
          acc[mf][nf] = __builtin_amdgcn_mfma_f32_16x16x32_bf16(a[mf], bfr[nf], acc[mf][nf], 0, 0, 0);
    }

#pragma unroll
    for (int mf = 0; mf < 2; ++mf) {
#pragma unroll
      for (int nf = 0; nf < 2; ++nf) {
        int p = n0 + wc * 32 + nf * 16 + col;
        int hw = p - b * HW_;
#pragma unroll
        for (int reg = 0; reg < 4; ++reg) {
          int o = m0 + wr * 32 + mf * 16 + kg * 4 + reg;
          float a = acc[mf][nf][reg];
          float rr = a * fminf(fmaxf(a + 3.f, 0.f), 6.f) * (1.f / 6.f);
          out[((size_t)b * O_ + o) * HW_ + hw] = rr;
        }
      }
    }
  }
}

extern "C" void kernel_launch(void* const* d_in, const int* in_sizes, int n_in,
                              void* d_out, int out_size, void* d_ws, size_t ws_size,
                              hipStream_t stream) {
  const float* x = (const float*)d_in[0];
  const float* og_dw = (const float*)d_in[1];
  const float* og_pw = (const float*)d_in[2];
  const float* dcn_w = (const float*)d_in[3];
  const float* pw_w = (const float*)d_in[4];
  float* out = (float*)d_out;

  float* ws = (float*)d_ws;
  float* offp3 = ws;                                     // 3*B*18*HW f32
  float* dcnT_g = offp3 + 3 * (size_t)B_ * NOFF * HW_;   // 9*C f32
  unsigned short* y1t = (unsigned short*)(dcnT_g + 9 * C_);  // NPIX*C bf16
  unsigned short* wtb = y1t + (size_t)NPIX * C_;         // O*C bf16
  unsigned short* x_t = wtb + (size_t)O_ * C_;           // NPIX*C bf16
  unsigned short* w2b = x_t + (size_t)NPIX * C_;         // 32*1728 bf16

  k_xtp<<<dim3(HW_ / 64, B_), TPB, 0, stream>>>(x, og_dw, og_pw, pw_w, dcn_w,
                                                x_t, wtb, w2b, dcnT_g);
  k_off2s<<<dim3(W_ / 8, H_ / 8, B_ * 3), TPB, 0, stream>>>(x_t, w2b, offp3);
  k_deform11<<<196 * 4 * B_ / 8, 512, 0, stream>>>(x_t, offp3, dcnT_g, y1t);
  k_gemm5<<<NPIX / 64 * 2, TPB, 0, stream>>>(y1t, wtb, out);
}